// Round 5
// baseline (232.783 us; speedup 1.0000x reference)
//
#include <hip/hip_runtime.h>
#include <math.h>

// Problem constants (from reference)
#define NNB 16   // neighbors
#define NOB 8    // obstacles
#define SDIM 4   // state dim
#define H1D 64   // hidden 1
#define ED 16    // embedding
#define HPD 64   // psi hidden
#define XW (1 + SDIM + SDIM*NNB + 2*NOB)  // 85 floats per row

// ---- LDS weight-pack layout (floats) ----
// A   : 64 k x 8  : [Wp1n[0..3][k], bp1n[k], Wp1o[0][k], Wp1o[1][k], bp1o[k]]
// W2N : 64 k x 16 : Wp2n row k (native row-major)
// W2O : 64 k x 16 : Wp2o row k
// R   : 64 k x 68 : [Wr1n col k (16) | Wr2n row k (16) | Wr1o col k (16) |
//                    Wr2o row k (16) | br1n[k], br1o[k], pad, pad]
// P   : 64 k x 40 : [Wpsi1 col k (36) | bpsi1[k] | pad | Wpsi2[k][0..1]]
// S   : bp2n(16) bp2o(16) br2n(16) br2o(16) bpsi2(2)
#define OFF_A    0
#define OFF_W2N  512
#define OFF_W2O  1536
#define OFF_R    2560      // 64*68 = 4352
#define OFF_P    6912      // 64*40 = 2560
#define OFF_S    9472      // 66
#define LDS_FLOATS 9538    // ~38.2 KB

__device__ __forceinline__ float fast_rcp(float x) { return __builtin_amdgcn_rcpf(x); }
__device__ __forceinline__ float fast_sqrt(float x) { return __builtin_amdgcn_sqrtf(x); }

// 2*tanh(a), overflow-safe, ~1e-6 rel err (output compared at bf16 granularity)
__device__ __forceinline__ float two_tanh(float a) {
    float ax = fabsf(a);
    float e = __expf(2.0f * ax);
    float t = 1.0f - 2.0f * fast_rcp(e + 1.0f);
    return copysignf(2.0f * t, a);
}

__global__ __launch_bounds__(256, 2) void barrier_net_kernel(
    const float* __restrict__ x,
    const float* __restrict__ Wp1n, const float* __restrict__ bp1n,
    const float* __restrict__ Wp2n, const float* __restrict__ bp2n,
    const float* __restrict__ Wr1n, const float* __restrict__ br1n,
    const float* __restrict__ Wr2n, const float* __restrict__ br2n,
    const float* __restrict__ Wp1o, const float* __restrict__ bp1o,
    const float* __restrict__ Wp2o, const float* __restrict__ bp2o,
    const float* __restrict__ Wr1o, const float* __restrict__ br1o,
    const float* __restrict__ Wr2o, const float* __restrict__ br2o,
    const float* __restrict__ Wpsi1, const float* __restrict__ bpsi1,
    const float* __restrict__ Wpsi2, const float* __restrict__ bpsi2,
    float* __restrict__ out, int nb)
{
    __shared__ __align__(16) float lds[LDS_FLOATS];
    const int tid = threadIdx.x;

    // ---------------- one-time cooperative weight staging -------------------
    for (int i = tid; i < 512; i += 256) {
        int k = i >> 3, c = i & 7;
        float v;
        if (c < 4)       v = Wp1n[c*H1D + k];
        else if (c == 4) v = bp1n[k];
        else if (c < 7)  v = Wp1o[(c-5)*H1D + k];
        else             v = bp1o[k];
        lds[OFF_A + i] = v;
    }
    for (int i = tid; i < 1024; i += 256) lds[OFF_W2N + i] = Wp2n[i];
    for (int i = tid; i < 1024; i += 256) lds[OFF_W2O + i] = Wp2o[i];
    for (int i = tid; i < 64*68; i += 256) {
        int k = i / 68, c = i - k*68;
        float v;
        if (c < 16)       v = Wr1n[c*H1D + k];
        else if (c < 32)  v = Wr2n[k*ED + (c-16)];
        else if (c < 48)  v = Wr1o[(c-32)*H1D + k];
        else if (c < 64)  v = Wr2o[k*ED + (c-48)];
        else if (c == 64) v = br1n[k];
        else if (c == 65) v = br1o[k];
        else              v = 0.f;
        lds[OFF_R + i] = v;
    }
    for (int i = tid; i < 64*40; i += 256) {
        int k = i / 40, c = i - k*40;
        float v;
        if (c < 36)       v = Wpsi1[c*HPD + k];
        else if (c == 36) v = bpsi1[k];
        else if (c == 38) v = Wpsi2[k*2 + 0];
        else if (c == 39) v = Wpsi2[k*2 + 1];
        else              v = 0.f;
        lds[OFF_P + i] = v;
    }
    if (tid < 16) {
        lds[OFF_S +  0 + tid] = bp2n[tid];
        lds[OFF_S + 16 + tid] = bp2o[tid];
        lds[OFF_S + 32 + tid] = br2n[tid];
        lds[OFF_S + 48 + tid] = br2o[tid];
    }
    if (tid < 2) lds[OFF_S + 64 + tid] = bpsi2[tid];
    __syncthreads();

    int row = blockIdx.x * blockDim.x + tid;
    if (row >= nb) return;
    const float* xr = x + (size_t)row * XW;

    // goal vector
    float g0 = xr[1], g1 = xr[2], g2 = xr[3], g3 = xr[4];

    // ---- all neighbor coords in registers ----
    float e0[NNB], e1[NNB], e2[NNB], e3[NNB];
    #pragma unroll
    for (int n = 0; n < NNB; ++n) {
        e0[n] = xr[1 + SDIM + n*SDIM + 0];
        e1[n] = xr[1 + SDIM + n*SDIM + 1];
        e2[n] = xr[1 + SDIM + n*SDIM + 2];
        e3[n] = xr[1 + SDIM + n*SDIM + 3];
    }
    const int obs_off = 1 + SDIM + SDIM*NNB;  // 69
    float o0[NOB], o1[NOB];
    #pragma unroll
    for (int n = 0; n < NOB; ++n) {
        o0[n] = xr[obs_off + n*2 + 0];
        o1[n] = xr[obs_off + n*2 + 1];
    }

    // ---- barrier sums (fast rcp/sqrt: ~1ulp, invisible at bf16 compare) ----
    float barx = 0.f, bary = 0.f;
    #pragma unroll
    for (int n = 0; n < NNB; ++n) {
        float px = -e0[n], py = -e1[n];
        float nrm = fast_sqrt(px*px + py*py);
        float coef = 0.05f * fast_rcp(nrm * (nrm - 0.3f));
        barx = fmaf(coef, px, barx);
        bary = fmaf(coef, py, bary);
    }
    #pragma unroll
    for (int n = 0; n < NOB; ++n) {
        float px = -o0[n], py = -o1[n];
        float nrm = fast_sqrt(px*px + py*py);
        float coef = 0.05f * fast_rcp(nrm * (nrm - 0.3f));
        barx = fmaf(coef, px, barx);
        bary = fmaf(coef, py, bary);
    }

    // ---------------- merged phi loop (sum-before-matmul identity) ----------
    float phin[ED], phio[ED];
    #pragma unroll
    for (int j = 0; j < ED; ++j) { phin[j] = 0.f; phio[j] = 0.f; }

    #pragma unroll 2
    for (int k = 0; k < H1D; ++k) {
        float4 a0 = *(const float4*)(lds + OFF_A + k*8);
        float4 a1 = *(const float4*)(lds + OFF_A + k*8 + 4);
        // neighbor hidden-sum
        float hn[NNB];
        #pragma unroll
        for (int n = 0; n < NNB; ++n) {
            float v = fmaf(e3[n], a0.w, fmaf(e2[n], a0.z,
                      fmaf(e1[n], a0.y, fmaf(e0[n], a0.x, a1.x))));
            hn[n] = fmaxf(v, 0.f);
        }
        #pragma unroll
        for (int s = NNB/2; s > 0; s >>= 1)
            #pragma unroll
            for (int n = 0; n < s; ++n) hn[n] += hn[n+s];
        float sn = hn[0];
        // obstacle hidden-sum
        float ho[NOB];
        #pragma unroll
        for (int n = 0; n < NOB; ++n) {
            float v = fmaf(o1[n], a1.z, fmaf(o0[n], a1.y, a1.w));
            ho[n] = fmaxf(v, 0.f);
        }
        #pragma unroll
        for (int s = NOB/2; s > 0; s >>= 1)
            #pragma unroll
            for (int n = 0; n < s; ++n) ho[n] += ho[n+s];
        float so = ho[0];

        const float4* w2n = (const float4*)(lds + OFF_W2N + k*ED);
        const float4* w2o = (const float4*)(lds + OFF_W2O + k*ED);
        #pragma unroll
        for (int jv = 0; jv < 4; ++jv) {
            float4 pn = w2n[jv], po = w2o[jv];
            phin[jv*4+0] = fmaf(sn, pn.x, phin[jv*4+0]);
            phin[jv*4+1] = fmaf(sn, pn.y, phin[jv*4+1]);
            phin[jv*4+2] = fmaf(sn, pn.z, phin[jv*4+2]);
            phin[jv*4+3] = fmaf(sn, pn.w, phin[jv*4+3]);
            phio[jv*4+0] = fmaf(so, po.x, phio[jv*4+0]);
            phio[jv*4+1] = fmaf(so, po.y, phio[jv*4+1]);
            phio[jv*4+2] = fmaf(so, po.z, phio[jv*4+2]);
            phio[jv*4+3] = fmaf(so, po.w, phio[jv*4+3]);
        }
    }
    #pragma unroll
    for (int j = 0; j < ED; ++j) {
        phin[j] = fmaf((float)NNB, lds[OFF_S + j],      phin[j]);
        phio[j] = fmaf((float)NOB, lds[OFF_S + 16 + j], phio[j]);
    }

    // ---------------- rho_n / rho_o merged k-loop ---------------------------
    float rhon[ED], rhoo[ED];
    #pragma unroll
    for (int j = 0; j < ED; ++j) {
        rhon[j] = lds[OFF_S + 32 + j];
        rhoo[j] = lds[OFF_S + 48 + j];
    }

    #pragma unroll 2
    for (int k = 0; k < H1D; ++k) {
        const float* Rk = lds + OFF_R + k*68;
        const float4* R4 = (const float4*)Rk;
        float4 w0 = R4[0], w1 = R4[1], w2 = R4[2], w3 = R4[3];      // Wr1n col
        float4 u0 = R4[8], u1 = R4[9], u2 = R4[10], u3 = R4[11];    // Wr1o col
        float bn = Rk[64], bo = Rk[65];

        float sn0 = fmaf(phin[3], w0.w, fmaf(phin[2], w0.z, fmaf(phin[1], w0.y, fmaf(phin[0], w0.x, bn))));
        float sn1 = fmaf(phin[7], w1.w, fmaf(phin[6], w1.z, fmaf(phin[5], w1.y, phin[4]*w1.x)));
        float sn2 = fmaf(phin[11], w2.w, fmaf(phin[10], w2.z, fmaf(phin[9], w2.y, phin[8]*w2.x)));
        float sn3 = fmaf(phin[15], w3.w, fmaf(phin[14], w3.z, fmaf(phin[13], w3.y, phin[12]*w3.x)));
        float so0 = fmaf(phio[3], u0.w, fmaf(phio[2], u0.z, fmaf(phio[1], u0.y, fmaf(phio[0], u0.x, bo))));
        float so1 = fmaf(phio[7], u1.w, fmaf(phio[6], u1.z, fmaf(phio[5], u1.y, phio[4]*u1.x)));
        float so2 = fmaf(phio[11], u2.w, fmaf(phio[10], u2.z, fmaf(phio[9], u2.y, phio[8]*u2.x)));
        float so3 = fmaf(phio[15], u3.w, fmaf(phio[14], u3.z, fmaf(phio[13], u3.y, phio[12]*u3.x)));
        float hn = fmaxf((sn0 + sn1) + (sn2 + sn3), 0.f);
        float ho = fmaxf((so0 + so1) + (so2 + so3), 0.f);

        #pragma unroll
        for (int jv = 0; jv < 4; ++jv) {
            float4 rn = R4[4 + jv];    // Wr2n row
            float4 ro = R4[12 + jv];   // Wr2o row
            rhon[jv*4+0] = fmaf(hn, rn.x, rhon[jv*4+0]);
            rhon[jv*4+1] = fmaf(hn, rn.y, rhon[jv*4+1]);
            rhon[jv*4+2] = fmaf(hn, rn.z, rhon[jv*4+2]);
            rhon[jv*4+3] = fmaf(hn, rn.w, rhon[jv*4+3]);
            rhoo[jv*4+0] = fmaf(ho, ro.x, rhoo[jv*4+0]);
            rhoo[jv*4+1] = fmaf(ho, ro.y, rhoo[jv*4+1]);
            rhoo[jv*4+2] = fmaf(ho, ro.z, rhoo[jv*4+2]);
            rhoo[jv*4+3] = fmaf(ho, ro.w, rhoo[jv*4+3]);
        }
    }

    // ---------------- psi head: h = [rho_n, rho_o, g] (36) ------------------
    float a0 = lds[OFF_S + 64], a1 = lds[OFF_S + 65];
    #pragma unroll 2
    for (int k = 0; k < HPD; ++k) {
        const float* Pk = lds + OFF_P + k*40;
        const float4* P4 = (const float4*)Pk;
        float4 c0 = P4[0], c1 = P4[1], c2 = P4[2], c3 = P4[3];
        float s0 = fmaf(rhon[3], c0.w, fmaf(rhon[2], c0.z, fmaf(rhon[1], c0.y, fmaf(rhon[0], c0.x, Pk[36]))));
        float s1 = fmaf(rhon[7], c1.w, fmaf(rhon[6], c1.z, fmaf(rhon[5], c1.y, rhon[4]*c1.x)));
        float s2 = fmaf(rhon[11], c2.w, fmaf(rhon[10], c2.z, fmaf(rhon[9], c2.y, rhon[8]*c2.x)));
        float s3 = fmaf(rhon[15], c3.w, fmaf(rhon[14], c3.z, fmaf(rhon[13], c3.y, rhon[12]*c3.x)));
        float4 c4 = P4[4], c5 = P4[5], c6 = P4[6], c7 = P4[7];
        s0 = fmaf(rhoo[3], c4.w, fmaf(rhoo[2], c4.z, fmaf(rhoo[1], c4.y, fmaf(rhoo[0], c4.x, s0))));
        s1 = fmaf(rhoo[7], c5.w, fmaf(rhoo[6], c5.z, fmaf(rhoo[5], c5.y, fmaf(rhoo[4], c5.x, s1))));
        s2 = fmaf(rhoo[11], c6.w, fmaf(rhoo[10], c6.z, fmaf(rhoo[9], c6.y, fmaf(rhoo[8], c6.x, s2))));
        s3 = fmaf(rhoo[15], c7.w, fmaf(rhoo[14], c7.z, fmaf(rhoo[13], c7.y, fmaf(rhoo[12], c7.x, s3))));
        float4 c8 = P4[8];
        s0 = fmaf(g0, c8.x, s0);
        s1 = fmaf(g1, c8.y, s1);
        s2 = fmaf(g2, c8.z, s2);
        s3 = fmaf(g3, c8.w, s3);
        float h = fmaxf((s0 + s1) + (s2 + s3), 0.f);
        a0 = fmaf(h, Pk[38], a0);
        a1 = fmaf(h, Pk[39], a1);
    }

    // emp = 2*tanh(a); action = emp + barrier; normalize
    a0 = two_tanh(a0) + barx;
    a1 = two_tanh(a1) + bary;
    float amax = fmaxf(fabsf(a0), fabsf(a1));
    float inv_alpha = fmaxf(amax * 0.5f, 1.0f);  // A_MAX = 2.0
    float r = fast_rcp(inv_alpha);

    out[(size_t)row*2 + 0] = a0 * r;
    out[(size_t)row*2 + 1] = a1 * r;
}

extern "C" void kernel_launch(void* const* d_in, const int* in_sizes, int n_in,
                              void* d_out, int out_size, void* d_ws, size_t ws_size,
                              hipStream_t stream) {
    const float* x     = (const float*)d_in[0];
    const float* Wp1n  = (const float*)d_in[1];
    const float* bp1n  = (const float*)d_in[2];
    const float* Wp2n  = (const float*)d_in[3];
    const float* bp2n  = (const float*)d_in[4];
    const float* Wr1n  = (const float*)d_in[5];
    const float* br1n  = (const float*)d_in[6];
    const float* Wr2n  = (const float*)d_in[7];
    const float* br2n  = (const float*)d_in[8];
    const float* Wp1o  = (const float*)d_in[9];
    const float* bp1o  = (const float*)d_in[10];
    const float* Wp2o  = (const float*)d_in[11];
    const float* bp2o  = (const float*)d_in[12];
    const float* Wr1o  = (const float*)d_in[13];
    const float* br1o  = (const float*)d_in[14];
    const float* Wr2o  = (const float*)d_in[15];
    const float* br2o  = (const float*)d_in[16];
    const float* Wpsi1 = (const float*)d_in[17];
    const float* bpsi1 = (const float*)d_in[18];
    const float* Wpsi2 = (const float*)d_in[19];
    const float* bpsi2 = (const float*)d_in[20];
    float* out = (float*)d_out;

    int nb = in_sizes[0] / XW;   // 131072
    int block = 256;
    int grid = (nb + block - 1) / block;
    barrier_net_kernel<<<grid, block, 0, stream>>>(
        x, Wp1n, bp1n, Wp2n, bp2n, Wr1n, br1n, Wr2n, br2n,
        Wp1o, bp1o, Wp2o, bp2o, Wr1o, br1o, Wr2o, br2o,
        Wpsi1, bpsi1, Wpsi2, bpsi2, out, nb);
}

// Round 6
// 222.043 us; speedup vs baseline: 1.0484x; 1.0484x over previous
//
#include <hip/hip_runtime.h>
#include <math.h>

// Problem constants (from reference)
#define NNB 16   // neighbors
#define NOB 8    // obstacles
#define SDIM 4   // state dim
#define H1D 64   // hidden 1
#define ED 16    // embedding
#define HPD 64   // psi hidden
#define XW (1 + SDIM + SDIM*NNB + 2*NOB)  // 85 floats per row

__device__ __forceinline__ float fast_rcp(float x) { return __builtin_amdgcn_rcpf(x); }
__device__ __forceinline__ float fast_sqrt(float x) { return __builtin_amdgcn_sqrtf(x); }

// 2*tanh(a), overflow-safe, ~1e-6 rel err (output compared at bf16 granularity)
__device__ __forceinline__ float two_tanh(float a) {
    float ax = fabsf(a);
    float e = __expf(2.0f * ax);
    float t = 1.0f - 2.0f * fast_rcp(e + 1.0f);
    return copysignf(2.0f * t, a);
}

// ---------------------------------------------------------------------------
// K1: phi (sum-before-matmul identity) + barrier terms.
// Weight working set: 4*64 + 64 + 2*64 + 64 + 2*64*16 + 2*16 floats ~ 10.2 KB
// -> fits scalar cache; all weight loads are wave-uniform s_loads that HIT.
// Outputs column-major [j][row] so downstream reads/writes are coalesced.
// ---------------------------------------------------------------------------
__global__ __launch_bounds__(256, 2) void k_phi(
    const float* __restrict__ x,
    const float* __restrict__ Wp1n, const float* __restrict__ bp1n,
    const float* __restrict__ Wp2n, const float* __restrict__ bp2n,
    const float* __restrict__ Wp1o, const float* __restrict__ bp1o,
    const float* __restrict__ Wp2o, const float* __restrict__ bp2o,
    float* __restrict__ phin_g, float* __restrict__ phio_g,
    float* __restrict__ bar_g, int nb)
{
    int row = blockIdx.x * blockDim.x + threadIdx.x;
    if (row >= nb) return;
    const float* xr = x + (size_t)row * XW;

    float e0[NNB], e1[NNB], e2[NNB], e3[NNB];
    #pragma unroll
    for (int n = 0; n < NNB; ++n) {
        e0[n] = xr[1 + SDIM + n*SDIM + 0];
        e1[n] = xr[1 + SDIM + n*SDIM + 1];
        e2[n] = xr[1 + SDIM + n*SDIM + 2];
        e3[n] = xr[1 + SDIM + n*SDIM + 3];
    }
    const int obs_off = 1 + SDIM + SDIM*NNB;  // 69
    float o0[NOB], o1[NOB];
    #pragma unroll
    for (int n = 0; n < NOB; ++n) {
        o0[n] = xr[obs_off + n*2 + 0];
        o1[n] = xr[obs_off + n*2 + 1];
    }

    // barrier sums (fast rcp/sqrt: ~1ulp, invisible at bf16-granularity compare)
    float barx = 0.f, bary = 0.f;
    #pragma unroll
    for (int n = 0; n < NNB; ++n) {
        float px = -e0[n], py = -e1[n];
        float nrm = fast_sqrt(px*px + py*py);
        float coef = 0.05f * fast_rcp(nrm * (nrm - 0.3f));
        barx = fmaf(coef, px, barx);
        bary = fmaf(coef, py, bary);
    }
    #pragma unroll
    for (int n = 0; n < NOB; ++n) {
        float px = -o0[n], py = -o1[n];
        float nrm = fast_sqrt(px*px + py*py);
        float coef = 0.05f * fast_rcp(nrm * (nrm - 0.3f));
        barx = fmaf(coef, px, barx);
        bary = fmaf(coef, py, bary);
    }

    float phin[ED], phio[ED];
    #pragma unroll
    for (int j = 0; j < ED; ++j) { phin[j] = 0.f; phio[j] = 0.f; }

    #pragma unroll 2
    for (int k = 0; k < H1D; ++k) {
        float wn0 = Wp1n[0*H1D + k], wn1 = Wp1n[1*H1D + k];
        float wn2 = Wp1n[2*H1D + k], wn3 = Wp1n[3*H1D + k];
        float bn  = bp1n[k];
        float hn[NNB];
        #pragma unroll
        for (int n = 0; n < NNB; ++n) {
            float v = fmaf(e3[n], wn3, fmaf(e2[n], wn2, fmaf(e1[n], wn1, fmaf(e0[n], wn0, bn))));
            hn[n] = fmaxf(v, 0.f);
        }
        #pragma unroll
        for (int s = NNB/2; s > 0; s >>= 1)
            #pragma unroll
            for (int n = 0; n < s; ++n) hn[n] += hn[n+s];
        float sn = hn[0];

        float wo0 = Wp1o[0*H1D + k], wo1 = Wp1o[1*H1D + k];
        float bo  = bp1o[k];
        float ho[NOB];
        #pragma unroll
        for (int n = 0; n < NOB; ++n) {
            float v = fmaf(o1[n], wo1, fmaf(o0[n], wo0, bo));
            ho[n] = fmaxf(v, 0.f);
        }
        #pragma unroll
        for (int s = NOB/2; s > 0; s >>= 1)
            #pragma unroll
            for (int n = 0; n < s; ++n) ho[n] += ho[n+s];
        float so = ho[0];

        const float* w2n = Wp2n + k*ED;
        const float* w2o = Wp2o + k*ED;
        #pragma unroll
        for (int j = 0; j < ED; ++j) {
            phin[j] = fmaf(sn, w2n[j], phin[j]);
            phio[j] = fmaf(so, w2o[j], phio[j]);
        }
    }

    // fold stage-2 biases, write column-major (fully coalesced stores)
    #pragma unroll
    for (int j = 0; j < ED; ++j) {
        phin_g[(size_t)j*nb + row] = fmaf((float)NNB, bp2n[j], phin[j]);
        phio_g[(size_t)j*nb + row] = fmaf((float)NOB, bp2o[j], phio[j]);
    }
    bar_g[row]      = barx;
    bar_g[nb + row] = bary;
}

// ---------------------------------------------------------------------------
// K2: generic mlp2  rho = relu(phi @ W1 + b1) @ W2 + b2
// Weight working set: 2*64*16*4 + 64*4 + 16*4 ~ 8.2 KB -> fits scalar cache.
// phi/rho are column-major [j][row].
// ---------------------------------------------------------------------------
__global__ __launch_bounds__(256, 2) void k_rho(
    const float* __restrict__ phi_g,
    const float* __restrict__ W1, const float* __restrict__ b1,
    const float* __restrict__ W2, const float* __restrict__ b2,
    float* __restrict__ rho_g, int nb)
{
    int row = blockIdx.x * blockDim.x + threadIdx.x;
    if (row >= nb) return;

    float p[ED];
    #pragma unroll
    for (int j = 0; j < ED; ++j) p[j] = phi_g[(size_t)j*nb + row];

    float r[ED];
    #pragma unroll
    for (int j = 0; j < ED; ++j) r[j] = b2[j];

    #pragma unroll 2
    for (int k = 0; k < H1D; ++k) {
        float s0 = b1[k], s1 = 0.f, s2 = 0.f, s3 = 0.f;
        #pragma unroll
        for (int j = 0; j < ED; j += 4) {
            s0 = fmaf(p[j+0], W1[(j+0)*H1D + k], s0);
            s1 = fmaf(p[j+1], W1[(j+1)*H1D + k], s1);
            s2 = fmaf(p[j+2], W1[(j+2)*H1D + k], s2);
            s3 = fmaf(p[j+3], W1[(j+3)*H1D + k], s3);
        }
        float h = fmaxf((s0 + s1) + (s2 + s3), 0.f);
        const float* w2 = W2 + k*ED;
        #pragma unroll
        for (int j = 0; j < ED; ++j) r[j] = fmaf(h, w2[j], r[j]);
    }

    #pragma unroll
    for (int j = 0; j < ED; ++j) rho_g[(size_t)j*nb + row] = r[j];
}

// ---------------------------------------------------------------------------
// K3: psi head + tanh + barrier add + normalization.
// Weight working set: 36*64*4 + 64*4 + 64*2*4 + 8 ~ 9.8 KB -> fits.
// ---------------------------------------------------------------------------
__global__ __launch_bounds__(256, 2) void k_psi(
    const float* __restrict__ x,
    const float* __restrict__ rhon_g, const float* __restrict__ rhoo_g,
    const float* __restrict__ bar_g,
    const float* __restrict__ Wpsi1, const float* __restrict__ bpsi1,
    const float* __restrict__ Wpsi2, const float* __restrict__ bpsi2,
    float* __restrict__ out, int nb)
{
    int row = blockIdx.x * blockDim.x + threadIdx.x;
    if (row >= nb) return;
    const float* xr = x + (size_t)row * XW;
    float g0 = xr[1], g1 = xr[2], g2 = xr[3], g3 = xr[4];

    float rn[ED], ro[ED];
    #pragma unroll
    for (int j = 0; j < ED; ++j) rn[j] = rhon_g[(size_t)j*nb + row];
    #pragma unroll
    for (int j = 0; j < ED; ++j) ro[j] = rhoo_g[(size_t)j*nb + row];

    float a0 = bpsi2[0], a1 = bpsi2[1];
    #pragma unroll 2
    for (int k = 0; k < HPD; ++k) {
        float s0 = bpsi1[k], s1 = 0.f, s2 = 0.f, s3 = 0.f;
        #pragma unroll
        for (int j = 0; j < ED; j += 4) {
            s0 = fmaf(rn[j+0], Wpsi1[(j+0)*HPD + k], s0);
            s1 = fmaf(rn[j+1], Wpsi1[(j+1)*HPD + k], s1);
            s2 = fmaf(rn[j+2], Wpsi1[(j+2)*HPD + k], s2);
            s3 = fmaf(rn[j+3], Wpsi1[(j+3)*HPD + k], s3);
        }
        #pragma unroll
        for (int j = 0; j < ED; j += 4) {
            s0 = fmaf(ro[j+0], Wpsi1[(ED+j+0)*HPD + k], s0);
            s1 = fmaf(ro[j+1], Wpsi1[(ED+j+1)*HPD + k], s1);
            s2 = fmaf(ro[j+2], Wpsi1[(ED+j+2)*HPD + k], s2);
            s3 = fmaf(ro[j+3], Wpsi1[(ED+j+3)*HPD + k], s3);
        }
        s0 = fmaf(g0, Wpsi1[(2*ED + 0)*HPD + k], s0);
        s1 = fmaf(g1, Wpsi1[(2*ED + 1)*HPD + k], s1);
        s2 = fmaf(g2, Wpsi1[(2*ED + 2)*HPD + k], s2);
        s3 = fmaf(g3, Wpsi1[(2*ED + 3)*HPD + k], s3);
        float h = fmaxf((s0 + s1) + (s2 + s3), 0.f);
        a0 = fmaf(h, Wpsi2[k*2 + 0], a0);
        a1 = fmaf(h, Wpsi2[k*2 + 1], a1);
    }

    a0 = two_tanh(a0) + bar_g[row];
    a1 = two_tanh(a1) + bar_g[nb + row];
    float amax = fmaxf(fabsf(a0), fabsf(a1));
    float inv_alpha = fmaxf(amax * 0.5f, 1.0f);  // A_MAX = 2.0
    float r = fast_rcp(inv_alpha);

    out[(size_t)row*2 + 0] = a0 * r;
    out[(size_t)row*2 + 1] = a1 * r;
}

extern "C" void kernel_launch(void* const* d_in, const int* in_sizes, int n_in,
                              void* d_out, int out_size, void* d_ws, size_t ws_size,
                              hipStream_t stream) {
    const float* x     = (const float*)d_in[0];
    const float* Wp1n  = (const float*)d_in[1];
    const float* bp1n  = (const float*)d_in[2];
    const float* Wp2n  = (const float*)d_in[3];
    const float* bp2n  = (const float*)d_in[4];
    const float* Wr1n  = (const float*)d_in[5];
    const float* br1n  = (const float*)d_in[6];
    const float* Wr2n  = (const float*)d_in[7];
    const float* br2n  = (const float*)d_in[8];
    const float* Wp1o  = (const float*)d_in[9];
    const float* bp1o  = (const float*)d_in[10];
    const float* Wp2o  = (const float*)d_in[11];
    const float* bp2o  = (const float*)d_in[12];
    const float* Wr1o  = (const float*)d_in[13];
    const float* br1o  = (const float*)d_in[14];
    const float* Wr2o  = (const float*)d_in[15];
    const float* br2o  = (const float*)d_in[16];
    const float* Wpsi1 = (const float*)d_in[17];
    const float* bpsi1 = (const float*)d_in[18];
    const float* Wpsi2 = (const float*)d_in[19];
    const float* bpsi2 = (const float*)d_in[20];
    float* out = (float*)d_out;

    int nb = in_sizes[0] / XW;   // 131072

    // workspace carve-up (column-major intermediates), 66*nb floats ~ 34.6 MB
    float* w      = (float*)d_ws;
    float* phin_g = w;
    float* phio_g = w + (size_t)16*nb;
    float* rhon_g = w + (size_t)32*nb;
    float* rhoo_g = w + (size_t)48*nb;
    float* bar_g  = w + (size_t)64*nb;

    int block = 256;
    int grid = (nb + block - 1) / block;

    k_phi<<<grid, block, 0, stream>>>(x, Wp1n, bp1n, Wp2n, bp2n,
                                      Wp1o, bp1o, Wp2o, bp2o,
                                      phin_g, phio_g, bar_g, nb);
    k_rho<<<grid, block, 0, stream>>>(phin_g, Wr1n, br1n, Wr2n, br2n, rhon_g, nb);
    k_rho<<<grid, block, 0, stream>>>(phio_g, Wr1o, br1o, Wr2o, br2o, rhoo_g, nb);
    k_psi<<<grid, block, 0, stream>>>(x, rhon_g, rhoo_g, bar_g,
                                      Wpsi1, bpsi1, Wpsi2, bpsi2, out, nb);
}

// Round 7
// 198.516 us; speedup vs baseline: 1.1726x; 1.1185x over previous
//
#include <hip/hip_runtime.h>
#include <math.h>

// ---------------------------------------------------------------------------
// Barrier_Net as bf16 MFMA (16x16x32), split-bf16 (hi+lo) for ~fp32 accuracy.
// One wave handles 16 batch rows end-to-end; stages round-trip through
// wave-private LDS in [row][k] bf16-pair (hi|lo<<16 per u32) layout.
// A-frag: A[m=lane&15][k=(lane>>4)*8+j]; B-frag: B[k=(lane>>4)*8+j][n=lane&15]
// C/D: col=lane&15, row=(lane>>4)*4+reg   (per cdna_hip_programming.md §3)
// All K/N padding handled by zero-filled B-frags (junk A x 0 = 0; LDS pads
// zeroed so junk is finite).
// ---------------------------------------------------------------------------

typedef __attribute__((ext_vector_type(8))) short bf16x8;
typedef __attribute__((ext_vector_type(4))) float f32x4;

#define NNB 16
#define NOB 8
#define XW  85   // floats per input row

// ---- B-frag table in d_ws (prep kernel fills; 68 frags x 64 lanes x 8 bf16)
#define FR_S1N  0    // Wp1n (K=4,  N=64): [nt0..3]x[hi,lo]
#define FR_S1O  8    // Wp1o (K=2,  N=64)
#define FR_G2N  16   // Wp2n (K=64, N=16): [kk0..1]x[hi,lo]
#define FR_G2O  20   // Wp2o
#define FR_RNA  24   // Wr1n (K=16, N=64): [nt]x[part]
#define FR_RNB  32   // Wr2n (K=64, N=16)
#define FR_ROA  36   // Wr1o
#define FR_ROB  44   // Wr2o
#define FR_PSI1 48   // Wpsi1(K=36, N=64): [kk][nt][part]
#define FR_PSI2 64   // Wpsi2(K=64, N=2)
#define N_FRAGS 68

// ---- per-wave LDS layout (bytes) ----
#define L_BIG   0     // 16 rows x 272 B (64 pairs + 16B pad)  : Sn/h2/h3
#define L_PHI   4352  // 16 rows x 80 B  (16 pairs + pad), 1408 total
#define L_CAT   5760  // 16 rows x 176 B (36 pairs + pad), 2912 total
#define L_OUT   8672  // 16 x 8 B  (a0,a1 fp32)
#define L_BARN  8800  // 16 x 8 B  (nbr barrier x,y)
#define L_BARO  8928  // 16 x 8 B  (obs barrier x,y)
#define WAVE_LDS 9088

__device__ __forceinline__ float fast_rcp(float x)  { return __builtin_amdgcn_rcpf(x); }
__device__ __forceinline__ float fast_sqrt(float x) { return __builtin_amdgcn_sqrtf(x); }

__device__ __forceinline__ float two_tanh(float a) {
    float ax = fabsf(a);
    float e = __expf(2.0f * ax);
    float t = 1.0f - 2.0f * fast_rcp(e + 1.0f);
    return copysignf(2.0f * t, a);
}

__device__ __forceinline__ void lds_fence() {
    __asm__ __volatile__("s_waitcnt lgkmcnt(0)" ::: "memory");
}

// fp32 -> (hi bf16 | lo bf16 << 16); hi = truncate, lo = exact remainder
__device__ __forceinline__ unsigned pack_split(float v) {
    unsigned u = __float_as_uint(v);
    float lo = v - __uint_as_float(u & 0xffff0000u);   // exact
    return (u >> 16) | (__float_as_uint(lo) & 0xffff0000u);
}

struct AB { bf16x8 h, l; };

// read A-frag (hi+lo) from LDS [row][k] pair layout
__device__ __forceinline__ AB lds_afrag(const char* area, int stride, int kkbyte, int lane) {
    int m = lane & 15, q = lane >> 4;
    const char* p = area + m * stride + kkbyte + q * 32;
    uint4 a = *(const uint4*)(p);
    uint4 b = *(const uint4*)(p + 16);
    union { unsigned u[4]; bf16x8 v; } H, L;
    H.u[0] = (a.x & 0xffffu) | (a.y << 16);
    H.u[1] = (a.z & 0xffffu) | (a.w << 16);
    H.u[2] = (b.x & 0xffffu) | (b.y << 16);
    H.u[3] = (b.z & 0xffffu) | (b.w << 16);
    L.u[0] = (a.x >> 16) | (a.y & 0xffff0000u);
    L.u[1] = (a.z >> 16) | (a.w & 0xffff0000u);
    L.u[2] = (b.x >> 16) | (b.y & 0xffff0000u);
    L.u[3] = (b.z >> 16) | (b.w & 0xffff0000u);
    AB r; r.h = H.v; r.l = L.v; return r;
}

// build A-frag from 4 fp32 (k=0..3 real, rest 0). Extra quads land at k>=8
// where B is zero-filled -> harmless.
__device__ __forceinline__ AB make_a4(float f0, float f1, float f2, float f3) {
    unsigned u0 = __float_as_uint(f0), u1 = __float_as_uint(f1);
    unsigned u2 = __float_as_uint(f2), u3 = __float_as_uint(f3);
    float l0 = f0 - __uint_as_float(u0 & 0xffff0000u);
    float l1 = f1 - __uint_as_float(u1 & 0xffff0000u);
    float l2 = f2 - __uint_as_float(u2 & 0xffff0000u);
    float l3 = f3 - __uint_as_float(u3 & 0xffff0000u);
    union { unsigned u[4]; bf16x8 v; } H, L;
    H.u[0] = (u0 >> 16) | (u1 & 0xffff0000u);
    H.u[1] = (u2 >> 16) | (u3 & 0xffff0000u);
    H.u[2] = 0; H.u[3] = 0;
    L.u[0] = (__float_as_uint(l0) >> 16) | (__float_as_uint(l1) & 0xffff0000u);
    L.u[1] = (__float_as_uint(l2) >> 16) | (__float_as_uint(l3) & 0xffff0000u);
    L.u[2] = 0; L.u[3] = 0;
    AB r; r.h = H.v; r.l = L.v; return r;
}

__device__ __forceinline__ f32x4 mfma3(AB a, AB b, f32x4 c) {
    c = __builtin_amdgcn_mfma_f32_16x16x32_bf16(a.l, b.h, c, 0, 0, 0);
    c = __builtin_amdgcn_mfma_f32_16x16x32_bf16(a.h, b.l, c, 0, 0, 0);
    c = __builtin_amdgcn_mfma_f32_16x16x32_bf16(a.h, b.h, c, 0, 0, 0);
    return c;
}

__device__ __forceinline__ AB load_bfrag(const short* wsf, int frag, int lane) {
    const bf16x8* p = (const bf16x8*)(wsf + (size_t)frag * 512);
    AB r; r.h = p[2 * lane + 0]; r.h = r.h; // placeholder, replaced below
    // frags store hi and lo as SEPARATE frag ids; this helper loads one pair
    // (hi at frag, lo at frag+1)
    const bf16x8* ph = (const bf16x8*)(wsf + (size_t)frag * 512);
    const bf16x8* pl = (const bf16x8*)(wsf + (size_t)(frag + 1) * 512);
    r.h = ph[lane]; r.l = pl[lane];
    return r;
}

// ---------------------------------------------------------------------------
// prep: pack all weight matrices into MFMA B-frag blocks (bf16 hi/lo), zero
// padded outside (K,N). frag block = 64 lanes x 8 shorts.
// ---------------------------------------------------------------------------
__global__ void bn_prep(const float* __restrict__ Wp1n, const float* __restrict__ Wp2n,
                        const float* __restrict__ Wr1n, const float* __restrict__ Wr2n,
                        const float* __restrict__ Wp1o, const float* __restrict__ Wp2o,
                        const float* __restrict__ Wr1o, const float* __restrict__ Wr2o,
                        const float* __restrict__ Wpsi1, const float* __restrict__ Wpsi2,
                        short* __restrict__ wsf)
{
    int f = blockIdx.x;
    int lane = threadIdx.x;   // 64
    const float* W; int K, N, kk, nt, part, rel;
    if (f < 8)        { W = Wp1n;  K = 4;  N = 64; rel = f;      kk = 0;        nt = rel >> 1;      part = rel & 1; }
    else if (f < 16)  { W = Wp1o;  K = 2;  N = 64; rel = f - 8;  kk = 0;        nt = rel >> 1;      part = rel & 1; }
    else if (f < 20)  { W = Wp2n;  K = 64; N = 16; rel = f - 16; kk = rel >> 1; nt = 0;             part = rel & 1; }
    else if (f < 24)  { W = Wp2o;  K = 64; N = 16; rel = f - 20; kk = rel >> 1; nt = 0;             part = rel & 1; }
    else if (f < 32)  { W = Wr1n;  K = 16; N = 64; rel = f - 24; kk = 0;        nt = rel >> 1;      part = rel & 1; }
    else if (f < 36)  { W = Wr2n;  K = 64; N = 16; rel = f - 32; kk = rel >> 1; nt = 0;             part = rel & 1; }
    else if (f < 44)  { W = Wr1o;  K = 16; N = 64; rel = f - 36; kk = 0;        nt = rel >> 1;      part = rel & 1; }
    else if (f < 48)  { W = Wr2o;  K = 64; N = 16; rel = f - 44; kk = rel >> 1; nt = 0;             part = rel & 1; }
    else if (f < 64)  { W = Wpsi1; K = 36; N = 64; rel = f - 48; kk = rel >> 3; nt = (rel >> 1) & 3; part = rel & 1; }
    else              { W = Wpsi2; K = 64; N = 2;  rel = f - 64; kk = rel >> 1; nt = 0;             part = rel & 1; }

    int q = lane >> 4, c = lane & 15;
    short* dst = wsf + (size_t)f * 512 + lane * 8;
    for (int j = 0; j < 8; ++j) {
        int k = kk * 32 + q * 8 + j;
        int n = nt * 16 + c;
        float v = (k < K && n < N) ? W[k * N + n] : 0.f;
        unsigned u = __float_as_uint(v);
        short s;
        if (part == 0) s = (short)(u >> 16);
        else {
            float lo = v - __uint_as_float(u & 0xffff0000u);
            s = (short)(__float_as_uint(lo) >> 16);
        }
        dst[j] = s;
    }
}

// ---------------------------------------------------------------------------
// main kernel: 1 wave = 16 rows. block 256 = 4 waves.
// ---------------------------------------------------------------------------
__global__ __launch_bounds__(256) void bn_main(
    const float* __restrict__ x, const short* __restrict__ wsf,
    const float* __restrict__ bp1n, const float* __restrict__ bp2n,
    const float* __restrict__ br1n, const float* __restrict__ br2n,
    const float* __restrict__ bp1o, const float* __restrict__ bp2o,
    const float* __restrict__ br1o, const float* __restrict__ br2o,
    const float* __restrict__ bpsi1, const float* __restrict__ bpsi2,
    float* __restrict__ out, int nb)
{
    __shared__ char smem[4 * WAVE_LDS];
    const int lane = threadIdx.x & 63;
    const int wid  = threadIdx.x >> 6;
    const int group = blockIdx.x * 4 + wid;
    const int row0 = group * 16;
    if (row0 >= nb) return;

    char* Wl  = smem + wid * WAVE_LDS;
    char* BIG = Wl + L_BIG;
    char* PHI = Wl + L_PHI;
    char* CAT = Wl + L_CAT;
    char* OUTA = Wl + L_OUT;
    char* BARN = Wl + L_BARN;
    char* BARO = Wl + L_BARO;

    const int m = lane & 15, q = lane >> 4, c = m;

    // zero PHI/CAT (incl. pads) so junk A-reads are finite (0 x 0 = 0)
    for (int i = lane; i < 352; i += 64) ((unsigned*)PHI)[i] = 0;   // 1408 B
    for (int i = lane; i < 728; i += 64) ((unsigned*)CAT)[i] = 0;   // 2912 B
    lds_fence();

    // biases (per output column c, replicated across rows in C-init)
    float b_s1n[4], b_s1o[4], b_rna[4], b_roa[4], b_p1[4];
    #pragma unroll
    for (int nt = 0; nt < 4; ++nt) {
        b_s1n[nt] = bp1n[nt * 16 + c];
        b_s1o[nt] = bp1o[nt * 16 + c];
        b_rna[nt] = br1n[nt * 16 + c];
        b_roa[nt] = br1o[nt * 16 + c];
        b_p1[nt]  = bpsi1[nt * 16 + c];
    }
    float b_g2n = 16.f * bp2n[c];
    float b_g2o = 8.f * bp2o[c];
    float b_rnb = br2n[c];
    float b_rob = br2o[c];
    float b_p2  = (c < 2) ? bpsi2[c] : 0.f;

    // g -> CAT cols 32..35 (pairs), lanes 0..15 handle one row each
    if (lane < 16) {
        const float* xr = x + (size_t)(row0 + lane) * XW;
        unsigned p0 = pack_split(xr[1]), p1 = pack_split(xr[2]);
        unsigned p2 = pack_split(xr[3]), p3 = pack_split(xr[4]);
        uint4 gv; gv.x = p0; gv.y = p1; gv.z = p2; gv.w = p3;
        *(uint4*)(CAT + lane * 176 + 128) = gv;
    }

    // ================= S1N: neighbor stage-1 + nbr barrier ==================
    {
        AB B[4];
        #pragma unroll
        for (int nt = 0; nt < 4; ++nt) B[nt] = load_bfrag(wsf, FR_S1N + nt * 2, lane);
        for (int r = 0; r < 16; ++r) {
            const float* xr = x + (size_t)(row0 + r) * XW;
            float f0 = xr[5 + 4 * m], f1 = xr[6 + 4 * m];
            float f2 = xr[7 + 4 * m], f3 = xr[8 + 4 * m];
            // barrier term for (row r, nbr m) — all quads redundant
            {
                float px = -f0, py = -f1;
                float nrm = fast_sqrt(px * px + py * py);
                float coef = 0.05f * fast_rcp(nrm * (nrm - 0.3f));
                float bx = coef * px, by = coef * py;
                bx += __shfl_xor(bx, 1);  by += __shfl_xor(by, 1);
                bx += __shfl_xor(bx, 2);  by += __shfl_xor(by, 2);
                bx += __shfl_xor(bx, 4);  by += __shfl_xor(by, 4);
                bx += __shfl_xor(bx, 8);  by += __shfl_xor(by, 8);
                if (m == 0) { float2 bb; bb.x = bx; bb.y = by; *(float2*)(BARN + r * 8) = bb; }
            }
            AB A = make_a4(f0, f1, f2, f3);
            #pragma unroll
            for (int nt = 0; nt < 4; ++nt) {
                f32x4 cc; cc[0] = b_s1n[nt]; cc[1] = b_s1n[nt]; cc[2] = b_s1n[nt]; cc[3] = b_s1n[nt];
                cc = mfma3(A, B[nt], cc);
                float s = fmaxf(cc[0], 0.f) + fmaxf(cc[1], 0.f) + fmaxf(cc[2], 0.f) + fmaxf(cc[3], 0.f);
                s += __shfl_xor(s, 16);
                s += __shfl_xor(s, 32);
                *(unsigned*)(BIG + r * 272 + (nt * 16 + c) * 4) = pack_split(s);
            }
        }
    }
    lds_fence();

    // ================= G2N: Sn @ Wp2n -> phi_n (PHI) ========================
    {
        AB A0 = lds_afrag(BIG, 272, 0, lane);
        AB A1 = lds_afrag(BIG, 272, 128, lane);
        f32x4 cc; cc[0] = b_g2n; cc[1] = b_g2n; cc[2] = b_g2n; cc[3] = b_g2n;
        cc = mfma3(A0, load_bfrag(wsf, FR_G2N + 0, lane), cc);
        cc = mfma3(A1, load_bfrag(wsf, FR_G2N + 2, lane), cc);
        #pragma unroll
        for (int reg = 0; reg < 4; ++reg)
            *(unsigned*)(PHI + (q * 4 + reg) * 80 + c * 4) = pack_split(cc[reg]);
    }
    lds_fence();

    // ================= RNA: relu(phi_n @ Wr1n + b) -> h2 (BIG) ==============
    {
        AB A = lds_afrag(PHI, 80, 0, lane);   // K=16 real, junk x 0 beyond
        #pragma unroll
        for (int nt = 0; nt < 4; ++nt) {
            f32x4 cc; cc[0] = b_rna[nt]; cc[1] = b_rna[nt]; cc[2] = b_rna[nt]; cc[3] = b_rna[nt];
            cc = mfma3(A, load_bfrag(wsf, FR_RNA + nt * 2, lane), cc);
            #pragma unroll
            for (int reg = 0; reg < 4; ++reg)
                *(unsigned*)(BIG + (q * 4 + reg) * 272 + (nt * 16 + c) * 4) = pack_split(fmaxf(cc[reg], 0.f));
        }
    }
    lds_fence();

    // ================= RNB: h2 @ Wr2n + b -> rho_n (CAT cols 0..15) =========
    {
        AB A0 = lds_afrag(BIG, 272, 0, lane);
        AB A1 = lds_afrag(BIG, 272, 128, lane);
        f32x4 cc; cc[0] = b_rnb; cc[1] = b_rnb; cc[2] = b_rnb; cc[3] = b_rnb;
        cc = mfma3(A0, load_bfrag(wsf, FR_RNB + 0, lane), cc);
        cc = mfma3(A1, load_bfrag(wsf, FR_RNB + 2, lane), cc);
        #pragma unroll
        for (int reg = 0; reg < 4; ++reg)
            *(unsigned*)(CAT + (q * 4 + reg) * 176 + c * 4) = pack_split(cc[reg]);
    }
    lds_fence();

    // ================= S1O: obstacle stage-1 + obs barrier ==================
    {
        AB B[4];
        #pragma unroll
        for (int nt = 0; nt < 4; ++nt) B[nt] = load_bfrag(wsf, FR_S1O + nt * 2, lane);
        for (int t = 0; t < 8; ++t) {
            int lr = 2 * t + (m >> 3);             // local row for this sample
            const float* xr = x + (size_t)(row0 + lr) * XW;
            float f0 = xr[69 + 2 * (m & 7)], f1 = xr[70 + 2 * (m & 7)];
            {
                float px = -f0, py = -f1;
                float nrm = fast_sqrt(px * px + py * py);
                float coef = 0.05f * fast_rcp(nrm * (nrm - 0.3f));
                float bx = coef * px, by = coef * py;
                bx += __shfl_xor(bx, 1);  by += __shfl_xor(by, 1);
                bx += __shfl_xor(bx, 2);  by += __shfl_xor(by, 2);
                bx += __shfl_xor(bx, 4);  by += __shfl_xor(by, 4);
                if ((lane & 7) == 0) {
                    float2 bb; bb.x = bx; bb.y = by;
                    *(float2*)(BARO + (2 * t + ((lane >> 3) & 1)) * 8) = bb;
                }
            }
            AB A = make_a4(f0, f1, 0.f, 0.f);   // k=0,1 real; rest x 0
            #pragma unroll
            for (int nt = 0; nt < 4; ++nt) {
                f32x4 cc; cc[0] = b_s1o[nt]; cc[1] = b_s1o[nt]; cc[2] = b_s1o[nt]; cc[3] = b_s1o[nt];
                cc = mfma3(A, B[nt], cc);
                float s = fmaxf(cc[0], 0.f) + fmaxf(cc[1], 0.f) + fmaxf(cc[2], 0.f) + fmaxf(cc[3], 0.f);
                s += __shfl_xor(s, 16);   // q0+q1 -> row 2t ; q2+q3 -> row 2t+1
                *(unsigned*)(BIG + (2 * t + (q >> 1)) * 272 + (nt * 16 + c) * 4) = pack_split(s);
            }
        }
    }
    lds_fence();

    // ================= G2O -> PHI ===========================================
    {
        AB A0 = lds_afrag(BIG, 272, 0, lane);
        AB A1 = lds_afrag(BIG, 272, 128, lane);
        f32x4 cc; cc[0] = b_g2o; cc[1] = b_g2o; cc[2] = b_g2o; cc[3] = b_g2o;
        cc = mfma3(A0, load_bfrag(wsf, FR_G2O + 0, lane), cc);
        cc = mfma3(A1, load_bfrag(wsf, FR_G2O + 2, lane), cc);
        #pragma unroll
        for (int reg = 0; reg < 4; ++reg)
            *(unsigned*)(PHI + (q * 4 + reg) * 80 + c * 4) = pack_split(cc[reg]);
    }
    lds_fence();

    // ================= ROA -> BIG ===========================================
    {
        AB A = lds_afrag(PHI, 80, 0, lane);
        #pragma unroll
        for (int nt = 0; nt < 4; ++nt) {
            f32x4 cc; cc[0] = b_roa[nt]; cc[1] = b_roa[nt]; cc[2] = b_roa[nt]; cc[3] = b_roa[nt];
            cc = mfma3(A, load_bfrag(wsf, FR_ROA + nt * 2, lane), cc);
            #pragma unroll
            for (int reg = 0; reg < 4; ++reg)
                *(unsigned*)(BIG + (q * 4 + reg) * 272 + (nt * 16 + c) * 4) = pack_split(fmaxf(cc[reg], 0.f));
        }
    }
    lds_fence();

    // ================= ROB -> rho_o (CAT cols 16..31) =======================
    {
        AB A0 = lds_afrag(BIG, 272, 0, lane);
        AB A1 = lds_afrag(BIG, 272, 128, lane);
        f32x4 cc; cc[0] = b_rob; cc[1] = b_rob; cc[2] = b_rob; cc[3] = b_rob;
        cc = mfma3(A0, load_bfrag(wsf, FR_ROB + 0, lane), cc);
        cc = mfma3(A1, load_bfrag(wsf, FR_ROB + 2, lane), cc);
        #pragma unroll
        for (int reg = 0; reg < 4; ++reg)
            *(unsigned*)(CAT + (q * 4 + reg) * 176 + (16 + c) * 4) = pack_split(cc[reg]);
    }
    lds_fence();

    // ================= PSI1: [rho_n|rho_o|g] @ Wpsi1 -> h3 (BIG) ============
    {
        AB A0 = lds_afrag(CAT, 176, 0, lane);
        AB A1 = lds_afrag(CAT, 176, 128, lane);
        #pragma unroll
        for (int nt = 0; nt < 4; ++nt) {
            f32x4 cc; cc[0] = b_p1[nt]; cc[1] = b_p1[nt]; cc[2] = b_p1[nt]; cc[3] = b_p1[nt];
            cc = mfma3(A0, load_bfrag(wsf, FR_PSI1 + (0 * 4 + nt) * 2, lane), cc);
            cc = mfma3(A1, load_bfrag(wsf, FR_PSI1 + (1 * 4 + nt) * 2, lane), cc);
            #pragma unroll
            for (int reg = 0; reg < 4; ++reg)
                *(unsigned*)(BIG + (q * 4 + reg) * 272 + (nt * 16 + c) * 4) = pack_split(fmaxf(cc[reg], 0.f));
        }
    }
    lds_fence();

    // ================= PSI2: h3 @ Wpsi2 -> a0,a1 ============================
    {
        AB A0 = lds_afrag(BIG, 272, 0, lane);
        AB A1 = lds_afrag(BIG, 272, 128, lane);
        f32x4 cc; cc[0] = b_p2; cc[1] = b_p2; cc[2] = b_p2; cc[3] = b_p2;
        cc = mfma3(A0, load_bfrag(wsf, FR_PSI2 + 0, lane), cc);
        cc = mfma3(A1, load_bfrag(wsf, FR_PSI2 + 2, lane), cc);
        if (c < 2) {
            #pragma unroll
            for (int reg = 0; reg < 4; ++reg)
                *(float*)(OUTA + (q * 4 + reg) * 8 + c * 4) = cc[reg];
        }
    }
    lds_fence();

    // ================= epilogue: tanh + barrier + normalize =================
    if (lane < 16) {
        float2 a  = *(const float2*)(OUTA + lane * 8);
        float2 bn = *(const float2*)(BARN + lane * 8);
        float2 bo = *(const float2*)(BARO + lane * 8);
        float a0 = two_tanh(a.x) + bn.x + bo.x;
        float a1 = two_tanh(a.y) + bn.y + bo.y;
        float amax = fmaxf(fabsf(a0), fabsf(a1));
        float inv_alpha = fmaxf(amax * 0.5f, 1.0f);
        float rr = fast_rcp(inv_alpha);
        float2 o; o.x = a0 * rr; o.y = a1 * rr;
        *(float2*)(out + (size_t)(row0 + lane) * 2) = o;
    }
}

extern "C" void kernel_launch(void* const* d_in, const int* in_sizes, int n_in,
                              void* d_out, int out_size, void* d_ws, size_t ws_size,
                              hipStream_t stream) {
    const float* x     = (const float*)d_in[0];
    const float* Wp1n  = (const float*)d_in[1];
    const float* bp1n  = (const float*)d_in[2];
    const float* Wp2n  = (const float*)d_in[3];
    const float* bp2n  = (const float*)d_in[4];
    const float* Wr1n  = (const float*)d_in[5];
    const float* br1n  = (const float*)d_in[6];
    const float* Wr2n  = (const float*)d_in[7];
    const float* br2n  = (const float*)d_in[8];
    const float* Wp1o  = (const float*)d_in[9];
    const float* bp1o  = (const float*)d_in[10];
    const float* Wp2o  = (const float*)d_in[11];
    const float* bp2o  = (const float*)d_in[12];
    const float* Wr1o  = (const float*)d_in[13];
    const float* br1o  = (const float*)d_in[14];
    const float* Wr2o  = (const float*)d_in[15];
    const float* br2o  = (const float*)d_in[16];
    const float* Wpsi1 = (const float*)d_in[17];
    const float* bpsi1 = (const float*)d_in[18];
    const float* Wpsi2 = (const float*)d_in[19];
    const float* bpsi2 = (const float*)d_in[20];
    float* out = (float*)d_out;

    int nb = in_sizes[0] / XW;               // 131072
    short* wsf = (short*)d_ws;               // 68 KB frag table

    bn_prep<<<N_FRAGS, 64, 0, stream>>>(Wp1n, Wp2n, Wr1n, Wr2n,
                                        Wp1o, Wp2o, Wr1o, Wr2o,
                                        Wpsi1, Wpsi2, wsf);

    int groups = (nb + 15) / 16;
    int blocks = (groups + 3) / 4;
    bn_main<<<blocks, 256, 0, stream>>>(x, wsf,
                                        bp1n, bp2n, br1n, br2n,
                                        bp1o, bp2o, br1o, br2o,
                                        bpsi1, bpsi2, out, nb);
}

// Round 8
// 176.402 us; speedup vs baseline: 1.3196x; 1.1254x over previous
//
#include <hip/hip_runtime.h>
#include <math.h>

// ---------------------------------------------------------------------------
// Barrier_Net via f16 MFMA (16x16x32), 2-term split:
//   A (activations) = hi+lo f16 (exact to ~22 bits), B (weights) = f16-rounded.
//   D = (A.l x B.h) + (A.h x B.h)  -> error ~ |A||W| 2^-11  (fp32 accumulate)
// One wave = 16 batch rows end-to-end; stages round-trip wave-private LDS in
// [row][k] f16-pair (hi | lo<<16 per u32) layout. No __syncthreads anywhere.
// A-frag: A[m=lane&15][k=(lane>>4)*8+j]; B-frag: B[k=(lane>>4)*8+j][n=lane&15]
// C/D: col=lane&15, row=(lane>>4)*4+reg.
// K/N padding via zero-filled B-frags (junk A x 0 = 0; junk kept finite by
// zero-initialized LDS pads).
// Latency plan: every stage's B-frags are loaded BEFORE the previous
// lds_fence (whose "memory" clobber pins them early -> ~200cyc overlap);
// S1N row loop is software-pipelined; barriers computed once up-front.
// ---------------------------------------------------------------------------

typedef __attribute__((ext_vector_type(8))) _Float16 f16x8;
typedef __attribute__((ext_vector_type(4))) float f32x4;

#define XW 85   // floats per input row

// ---- B-frag table in d_ws (hi at even frag id, lo at odd; lo unused now) ---
#define FR_S1N  0    // Wp1n (K=4,  N=64): [nt0..3]x[hi,lo]
#define FR_S1O  8    // Wp1o (K=2,  N=64)
#define FR_G2N  16   // Wp2n (K=64, N=16): [kk0..1]x[hi,lo]
#define FR_G2O  20   // Wp2o
#define FR_RNA  24   // Wr1n (K=16, N=64)
#define FR_RNB  32   // Wr2n (K=64, N=16)
#define FR_ROA  36   // Wr1o
#define FR_ROB  44   // Wr2o
#define FR_PSI1 48   // Wpsi1(K=36, N=64): [kk][nt][part]
#define FR_PSI2 64   // Wpsi2(K=64, N=2)
#define N_FRAGS 68

// ---- per-wave LDS layout (bytes) ----
#define L_BIG 0      // 16 rows x 272 B (64 pairs + 16 pad) : Sn / h2 / h3
#define L_PHI 4352   // 16 rows x 80 B  (16 pairs + pad), 1408 total
#define L_CAT 5760   // 16 rows x 176 B (36 pairs + pad), 2912 total
#define L_OUT 8672   // 16 x 8 B (a0,a1 fp32)
#define L_BAR 8800   // 16 x 8 B (barrier x,y summed n+o)
#define WAVE_LDS 8928

__device__ __forceinline__ float fast_rcp(float x)  { return __builtin_amdgcn_rcpf(x); }
__device__ __forceinline__ float fast_sqrt(float x) { return __builtin_amdgcn_sqrtf(x); }

__device__ __forceinline__ float two_tanh(float a) {
    float ax = fabsf(a);
    float e = __expf(2.0f * ax);
    float t = 1.0f - 2.0f * fast_rcp(e + 1.0f);
    return copysignf(2.0f * t, a);
}

__device__ __forceinline__ void lds_fence() {
    __asm__ __volatile__("s_waitcnt lgkmcnt(0)" ::: "memory");
}

union HU { _Float16 f; unsigned short u; };

// fp32 -> (f16 hi | f16 lo << 16); lo = f16(v - hi) captures next 11 bits
__device__ __forceinline__ unsigned pack_split(float v) {
    HU h, l;
    h.f = (_Float16)v;
    float r = v - (float)h.f;
    l.f = (_Float16)r;
    return (unsigned)h.u | ((unsigned)l.u << 16);
}

struct A2 { f16x8 h, l; };

// read A-frag (hi+lo) from LDS [row][k] pair layout; unpack via v_perm_b32
__device__ __forceinline__ A2 lds_afrag(const char* area, int stride, int kkbyte, int lane) {
    int m = lane & 15, q = lane >> 4;
    const char* p = area + m * stride + kkbyte + q * 32;
    uint4 a = *(const uint4*)(p);
    uint4 b = *(const uint4*)(p + 16);
    union { unsigned u[4]; f16x8 v; } H, L;
    H.u[0] = __builtin_amdgcn_perm(a.y, a.x, 0x05040100u);  // lo16(w0)|lo16(w1)<<16
    H.u[1] = __builtin_amdgcn_perm(a.w, a.z, 0x05040100u);
    H.u[2] = __builtin_amdgcn_perm(b.y, b.x, 0x05040100u);
    H.u[3] = __builtin_amdgcn_perm(b.w, b.z, 0x05040100u);
    L.u[0] = __builtin_amdgcn_perm(a.y, a.x, 0x07060302u);  // hi16(w0)|hi16(w1)<<16
    L.u[1] = __builtin_amdgcn_perm(a.w, a.z, 0x07060302u);
    L.u[2] = __builtin_amdgcn_perm(b.y, b.x, 0x07060302u);
    L.u[3] = __builtin_amdgcn_perm(b.w, b.z, 0x07060302u);
    A2 r; r.h = H.v; r.l = L.v; return r;
}

// A-frag from 4 fp32 (k=0..3 real, rest 0). Junk quads hit zero-filled B.
__device__ __forceinline__ A2 make_a4(float f0, float f1, float f2, float f3) {
    unsigned p0 = pack_split(f0), p1 = pack_split(f1);
    unsigned p2 = pack_split(f2), p3 = pack_split(f3);
    union { unsigned u[4]; f16x8 v; } H, L;
    H.u[0] = __builtin_amdgcn_perm(p1, p0, 0x05040100u);
    H.u[1] = __builtin_amdgcn_perm(p3, p2, 0x05040100u);
    H.u[2] = 0; H.u[3] = 0;
    L.u[0] = __builtin_amdgcn_perm(p1, p0, 0x07060302u);
    L.u[1] = __builtin_amdgcn_perm(p3, p2, 0x07060302u);
    L.u[2] = 0; L.u[3] = 0;
    A2 r; r.h = H.v; r.l = L.v; return r;
}

__device__ __forceinline__ f32x4 mfma2(A2 a, f16x8 bh, f32x4 c) {
    c = __builtin_amdgcn_mfma_f32_16x16x32_f16(a.l, bh, c, 0, 0, 0);
    c = __builtin_amdgcn_mfma_f32_16x16x32_f16(a.h, bh, c, 0, 0, 0);
    return c;
}

__device__ __forceinline__ f16x8 load_bh(const short* wsf, int frag, int lane) {
    return ((const f16x8*)(wsf + (size_t)frag * 512))[lane];
}

__device__ __forceinline__ f32x4 cinit(float b) {
    f32x4 c; c[0] = b; c[1] = b; c[2] = b; c[3] = b; return c;
}

// ---------------------------------------------------------------------------
// prep: pack weights into MFMA B-frag blocks (f16 hi/lo), zero outside (K,N).
// ---------------------------------------------------------------------------
__global__ void bn_prep(const float* __restrict__ Wp1n, const float* __restrict__ Wp2n,
                        const float* __restrict__ Wr1n, const float* __restrict__ Wr2n,
                        const float* __restrict__ Wp1o, const float* __restrict__ Wp2o,
                        const float* __restrict__ Wr1o, const float* __restrict__ Wr2o,
                        const float* __restrict__ Wpsi1, const float* __restrict__ Wpsi2,
                        short* __restrict__ wsf)
{
    int f = blockIdx.x;
    int lane = threadIdx.x;   // 64
    const float* W; int K, N, kk, nt, part, rel;
    if (f < 8)        { W = Wp1n;  K = 4;  N = 64; rel = f;      kk = 0;        nt = rel >> 1;       part = rel & 1; }
    else if (f < 16)  { W = Wp1o;  K = 2;  N = 64; rel = f - 8;  kk = 0;        nt = rel >> 1;       part = rel & 1; }
    else if (f < 20)  { W = Wp2n;  K = 64; N = 16; rel = f - 16; kk = rel >> 1; nt = 0;              part = rel & 1; }
    else if (f < 24)  { W = Wp2o;  K = 64; N = 16; rel = f - 20; kk = rel >> 1; nt = 0;              part = rel & 1; }
    else if (f < 32)  { W = Wr1n;  K = 16; N = 64; rel = f - 24; kk = 0;        nt = rel >> 1;       part = rel & 1; }
    else if (f < 36)  { W = Wr2n;  K = 64; N = 16; rel = f - 32; kk = rel >> 1; nt = 0;              part = rel & 1; }
    else if (f < 44)  { W = Wr1o;  K = 16; N = 64; rel = f - 36; kk = 0;        nt = rel >> 1;       part = rel & 1; }
    else if (f < 48)  { W = Wr2o;  K = 64; N = 16; rel = f - 44; kk = rel >> 1; nt = 0;              part = rel & 1; }
    else if (f < 64)  { W = Wpsi1; K = 36; N = 64; rel = f - 48; kk = rel >> 3; nt = (rel >> 1) & 3; part = rel & 1; }
    else              { W = Wpsi2; K = 64; N = 2;  rel = f - 64; kk = rel >> 1; nt = 0;              part = rel & 1; }

    int q = lane >> 4, c = lane & 15;
    short* dst = wsf + (size_t)f * 512 + lane * 8;
    for (int j = 0; j < 8; ++j) {
        int k = kk * 32 + q * 8 + j;
        int n = nt * 16 + c;
        float v = (k < K && n < N) ? W[k * N + n] : 0.f;
        HU h; h.f = (_Float16)v;
        short s;
        if (part == 0) s = (short)h.u;
        else {
            float r = v - (float)h.f;
            HU l; l.f = (_Float16)r;
            s = (short)l.u;
        }
        dst[j] = s;
    }
}

// ---------------------------------------------------------------------------
// main: 1 wave = 16 rows; block 256 = 4 waves.
// ---------------------------------------------------------------------------
__global__ __launch_bounds__(256) void bn_main(
    const float* __restrict__ x, const short* __restrict__ wsf,
    const float* __restrict__ bp1n, const float* __restrict__ bp2n,
    const float* __restrict__ br1n, const float* __restrict__ br2n,
    const float* __restrict__ bp1o, const float* __restrict__ bp2o,
    const float* __restrict__ br1o, const float* __restrict__ br2o,
    const float* __restrict__ bpsi1, const float* __restrict__ bpsi2,
    float* __restrict__ out, int nb)
{
    __shared__ char smem[4 * WAVE_LDS];
    const int lane = threadIdx.x & 63;
    const int wid  = threadIdx.x >> 6;
    const int group = blockIdx.x * 4 + wid;
    const int row0 = group * 16;
    if (row0 >= nb) return;

    char* Wl  = smem + wid * WAVE_LDS;
    char* BIG = Wl + L_BIG;
    char* PHI = Wl + L_PHI;
    char* CAT = Wl + L_CAT;
    char* OUTA = Wl + L_OUT;
    char* BAR  = Wl + L_BAR;

    const int m = lane & 15, q = lane >> 4, c = m;

    // zero PHI/CAT (pads must be finite for junk A-reads)
    for (int i = lane; i < 352; i += 64) ((unsigned*)PHI)[i] = 0;   // 1408 B
    for (int i = lane; i < 728; i += 64) ((unsigned*)CAT)[i] = 0;   // 2912 B
    lds_fence();

    // ---- barrier terms, fully parallel: lane (row=m, quad q) handles
    //      neighbors 4q..4q+3 and obstacles 2q..2q+1; 4 shuffles total ----
    {
        const float* xb = x + (size_t)(row0 + m) * XW;
        float bx = 0.f, by = 0.f;
        #pragma unroll
        for (int i = 0; i < 4; ++i) {
            int n = 4 * q + i;
            float px = -xb[5 + 4 * n], py = -xb[6 + 4 * n];
            float nrm = fast_sqrt(px * px + py * py);
            float coef = 0.05f * fast_rcp(nrm * (nrm - 0.3f));
            bx = fmaf(coef, px, bx);
            by = fmaf(coef, py, by);
        }
        #pragma unroll
        for (int i = 0; i < 2; ++i) {
            int o = 2 * q + i;
            float px = -xb[69 + 2 * o], py = -xb[70 + 2 * o];
            float nrm = fast_sqrt(px * px + py * py);
            float coef = 0.05f * fast_rcp(nrm * (nrm - 0.3f));
            bx = fmaf(coef, px, bx);
            by = fmaf(coef, py, by);
        }
        bx += __shfl_xor(bx, 16); by += __shfl_xor(by, 16);
        bx += __shfl_xor(bx, 32); by += __shfl_xor(by, 32);
        if (q == 0) { float2 bb; bb.x = bx; bb.y = by; *(float2*)(BAR + m * 8) = bb; }
    }

    // g -> CAT cols 32..35 (pairs)
    if (lane < 16) {
        const float* xr = x + (size_t)(row0 + lane) * XW;
        uint4 gv;
        gv.x = pack_split(xr[1]); gv.y = pack_split(xr[2]);
        gv.z = pack_split(xr[3]); gv.w = pack_split(xr[4]);
        *(uint4*)(CAT + lane * 176 + 128) = gv;
    }

    // biases (per output column c)
    float b_s1n[4], b_s1o[4], b_rna[4], b_roa[4], b_p1[4];
    #pragma unroll
    for (int nt = 0; nt < 4; ++nt) {
        b_s1n[nt] = bp1n[nt * 16 + c];
        b_s1o[nt] = bp1o[nt * 16 + c];
        b_rna[nt] = br1n[nt * 16 + c];
        b_roa[nt] = br1o[nt * 16 + c];
        b_p1[nt]  = bpsi1[nt * 16 + c];
    }
    float b_g2n = 16.f * bp2n[c];
    float b_g2o = 8.f * bp2o[c];
    float b_rnb = br2n[c];
    float b_rob = br2o[c];
    float b_p2  = (c < 2) ? bpsi2[c] : 0.f;

    // ---- stage-ahead B-frag loads for S1N + G2N ----
    f16x8 Bs1n[4], Bg2n[2];
    #pragma unroll
    for (int nt = 0; nt < 4; ++nt) Bs1n[nt] = load_bh(wsf, FR_S1N + nt * 2, lane);
    Bg2n[0] = load_bh(wsf, FR_G2N + 0, lane);
    Bg2n[1] = load_bh(wsf, FR_G2N + 2, lane);

    // ================= S1N: neighbor stage-1, software-pipelined ============
    {
        const float* xr0 = x + (size_t)row0 * XW + 5 + 4 * m;
        float c0 = xr0[0], c1 = xr0[1], c2 = xr0[2], c3 = xr0[3];
        #pragma unroll 4
        for (int r = 0; r < 16; ++r) {
            int rn = (r + 1) & 15;     // wraps to row0 at the end (harmless)
            const float* xrn = x + (size_t)(row0 + rn) * XW + 5 + 4 * m;
            float n0 = xrn[0], n1 = xrn[1], n2 = xrn[2], n3 = xrn[3];
            A2 A = make_a4(c0, c1, c2, c3);
            #pragma unroll
            for (int nt = 0; nt < 4; ++nt) {
                f32x4 cc = mfma2(A, Bs1n[nt], cinit(b_s1n[nt]));
                float s = fmaxf(cc[0], 0.f) + fmaxf(cc[1], 0.f)
                        + fmaxf(cc[2], 0.f) + fmaxf(cc[3], 0.f);
                s += __shfl_xor(s, 16);
                s += __shfl_xor(s, 32);
                *(unsigned*)(BIG + r * 272 + (nt * 16 + c) * 4) = pack_split(s);
            }
            c0 = n0; c1 = n1; c2 = n2; c3 = n3;
        }
    }
    // prefetch RNA B-frags before the fence (memory clobber pins them here)
    f16x8 Brna[4];
    #pragma unroll
    for (int nt = 0; nt < 4; ++nt) Brna[nt] = load_bh(wsf, FR_RNA + nt * 2, lane);
    lds_fence();

    // ================= G2N: Sn @ Wp2n -> phi_n (PHI) ========================
    {
        A2 A0 = lds_afrag(BIG, 272, 0, lane);
        A2 A1 = lds_afrag(BIG, 272, 128, lane);
        f32x4 ca = mfma2(A0, Bg2n[0], cinit(b_g2n));   // two independent chains
        f32x4 cb = mfma2(A1, Bg2n[1], cinit(0.f));
        #pragma unroll
        for (int reg = 0; reg < 4; ++reg)
            *(unsigned*)(PHI + (q * 4 + reg) * 80 + c * 4) = pack_split(ca[reg] + cb[reg]);
    }
    f16x8 Brnb[2], Bs1o[4];
    Brnb[0] = load_bh(wsf, FR_RNB + 0, lane);
    Brnb[1] = load_bh(wsf, FR_RNB + 2, lane);
    #pragma unroll
    for (int nt = 0; nt < 4; ++nt) Bs1o[nt] = load_bh(wsf, FR_S1O + nt * 2, lane);
    lds_fence();

    // ================= RNA: relu(phi_n @ Wr1n + b) -> h2 (BIG) ==============
    {
        A2 A = lds_afrag(PHI, 80, 0, lane);
        #pragma unroll
        for (int nt = 0; nt < 4; ++nt) {
            f32x4 cc = mfma2(A, Brna[nt], cinit(b_rna[nt]));
            #pragma unroll
            for (int reg = 0; reg < 4; ++reg)
                *(unsigned*)(BIG + (q * 4 + reg) * 272 + (nt * 16 + c) * 4) = pack_split(fmaxf(cc[reg], 0.f));
        }
    }
    // prefetch: G2O frags + all S1O x-data (used 2 stages ahead)
    f16x8 Bg2o[2];
    Bg2o[0] = load_bh(wsf, FR_G2O + 0, lane);
    Bg2o[1] = load_bh(wsf, FR_G2O + 2, lane);
    float of0[8], of1[8];
    #pragma unroll
    for (int t = 0; t < 8; ++t) {
        const float* xo = x + (size_t)(row0 + 2 * t + (m >> 3)) * XW + 69 + 2 * (m & 7);
        of0[t] = xo[0]; of1[t] = xo[1];
    }
    lds_fence();

    // ================= RNB: h2 @ Wr2n + b -> rho_n (CAT cols 0..15) =========
    {
        A2 A0 = lds_afrag(BIG, 272, 0, lane);
        A2 A1 = lds_afrag(BIG, 272, 128, lane);
        f32x4 ca = mfma2(A0, Brnb[0], cinit(b_rnb));
        f32x4 cb = mfma2(A1, Brnb[1], cinit(0.f));
        #pragma unroll
        for (int reg = 0; reg < 4; ++reg)
            *(unsigned*)(CAT + (q * 4 + reg) * 176 + c * 4) = pack_split(ca[reg] + cb[reg]);
    }
    f16x8 Broa[4];
    #pragma unroll
    for (int nt = 0; nt < 4; ++nt) Broa[nt] = load_bh(wsf, FR_ROA + nt * 2, lane);
    lds_fence();

    // ================= S1O: obstacle stage-1 ================================
    // lane m: rows 2t + (m>>3), obstacle m&7 as M dim; reg-sum + 1 shuffle
    {
        #pragma unroll
        for (int t = 0; t < 8; ++t) {
            A2 A = make_a4(of0[t], of1[t], 0.f, 0.f);
            #pragma unroll
            for (int nt = 0; nt < 4; ++nt) {
                f32x4 cc = mfma2(A, Bs1o[nt], cinit(b_s1o[nt]));
                float s = fmaxf(cc[0], 0.f) + fmaxf(cc[1], 0.f)
                        + fmaxf(cc[2], 0.f) + fmaxf(cc[3], 0.f);
                s += __shfl_xor(s, 16);   // q0+q1 -> row 2t ; q2+q3 -> row 2t+1
                *(unsigned*)(BIG + (2 * t + (q >> 1)) * 272 + (nt * 16 + c) * 4) = pack_split(s);
            }
        }
    }
    f16x8 Brob[2];
    Brob[0] = load_bh(wsf, FR_ROB + 0, lane);
    Brob[1] = load_bh(wsf, FR_ROB + 2, lane);
    lds_fence();

    // ================= G2O -> PHI ===========================================
    {
        A2 A0 = lds_afrag(BIG, 272, 0, lane);
        A2 A1 = lds_afrag(BIG, 272, 128, lane);
        f32x4 ca = mfma2(A0, Bg2o[0], cinit(b_g2o));
        f32x4 cb = mfma2(A1, Bg2o[1], cinit(0.f));
        #pragma unroll
        for (int reg = 0; reg < 4; ++reg)
            *(unsigned*)(PHI + (q * 4 + reg) * 80 + c * 4) = pack_split(ca[reg] + cb[reg]);
    }
    f16x8 Bp1a[4];   // PSI1 kk=0 frags
    #pragma unroll
    for (int nt = 0; nt < 4; ++nt) Bp1a[nt] = load_bh(wsf, FR_PSI1 + nt * 2, lane);
    lds_fence();

    // ================= ROA -> BIG ===========================================
    {
        A2 A = lds_afrag(PHI, 80, 0, lane);
        #pragma unroll
        for (int nt = 0; nt < 4; ++nt) {
            f32x4 cc = mfma2(A, Broa[nt], cinit(b_roa[nt]));
            #pragma unroll
            for (int reg = 0; reg < 4; ++reg)
                *(unsigned*)(BIG + (q * 4 + reg) * 272 + (nt * 16 + c) * 4) = pack_split(fmaxf(cc[reg], 0.f));
        }
    }
    f16x8 Bp1b[4], Bp2[2];   // PSI1 kk=1, PSI2
    #pragma unroll
    for (int nt = 0; nt < 4; ++nt) Bp1b[nt] = load_bh(wsf, FR_PSI1 + 8 + nt * 2, lane);
    Bp2[0] = load_bh(wsf, FR_PSI2 + 0, lane);
    Bp2[1] = load_bh(wsf, FR_PSI2 + 2, lane);
    lds_fence();

    // ================= ROB -> rho_o (CAT cols 16..31) =======================
    {
        A2 A0 = lds_afrag(BIG, 272, 0, lane);
        A2 A1 = lds_afrag(BIG, 272, 128, lane);
        f32x4 ca = mfma2(A0, Brob[0], cinit(b_rob));
        f32x4 cb = mfma2(A1, Brob[1], cinit(0.f));
        #pragma unroll
        for (int reg = 0; reg < 4; ++reg)
            *(unsigned*)(CAT + (q * 4 + reg) * 176 + (16 + c) * 4) = pack_split(ca[reg] + cb[reg]);
    }
    lds_fence();

    // ================= PSI1: [rho_n|rho_o|g] @ Wpsi1 -> h3 (BIG) ============
    {
        A2 A0 = lds_afrag(CAT, 176, 0, lane);
        A2 A1 = lds_afrag(CAT, 176, 128, lane);
        #pragma unroll
        for (int nt = 0; nt < 4; ++nt) {
            f32x4 ca = mfma2(A0, Bp1a[nt], cinit(b_p1[nt]));
            f32x4 cb = mfma2(A1, Bp1b[nt], cinit(0.f));
            #pragma unroll
            for (int reg = 0; reg < 4; ++reg)
                *(unsigned*)(BIG + (q * 4 + reg) * 272 + (nt * 16 + c) * 4) = pack_split(fmaxf(ca[reg] + cb[reg], 0.f));
        }
    }
    lds_fence();

    // ================= PSI2: h3 @ Wpsi2 -> a0,a1 ============================
    {
        A2 A0 = lds_afrag(BIG, 272, 0, lane);
        A2 A1 = lds_afrag(BIG, 272, 128, lane);
        f32x4 ca = mfma2(A0, Bp2[0], cinit(b_p2));
        f32x4 cb = mfma2(A1, Bp2[1], cinit(0.f));
        if (c < 2) {
            #pragma unroll
            for (int reg = 0; reg < 4; ++reg)
                *(float*)(OUTA + (q * 4 + reg) * 8 + c * 4) = ca[reg] + cb[reg];
        }
    }
    lds_fence();

    // ================= epilogue =============================================
    if (lane < 16) {
        float2 a  = *(const float2*)(OUTA + lane * 8);
        float2 bb = *(const float2*)(BAR + lane * 8);
        float a0 = two_tanh(a.x) + bb.x;
        float a1 = two_tanh(a.y) + bb.y;
        float amax = fmaxf(fabsf(a0), fabsf(a1));
        float inv_alpha = fmaxf(amax * 0.5f, 1.0f);
        float rr = fast_rcp(inv_alpha);
        float2 o; o.x = a0 * rr; o.y = a1 * rr;
        *(float2*)(out + (size_t)(row0 + lane) * 2) = o;
    }
}

extern "C" void kernel_launch(void* const* d_in, const int* in_sizes, int n_in,
                              void* d_out, int out_size, void* d_ws, size_t ws_size,
                              hipStream_t stream) {
    const float* x     = (const float*)d_in[0];
    const float* Wp1n  = (const float*)d_in[1];
    const float* bp1n  = (const float*)d_in[2];
    const float* Wp2n  = (const float*)d_in[3];
    const float* bp2n  = (const float*)d_in[4];
    const float* Wr1n  = (const float*)d_in[5];
    const float* br1n  = (const float*)d_in[6];
    const float* Wr2n  = (const float*)d_in[7];
    const float* br2n  = (const float*)d_in[8];
    const float* Wp1o  = (const float*)d_in[9];
    const float* bp1o  = (const float*)d_in[10];
    const float* Wp2o  = (const float*)d_in[11];
    const float* bp2o  = (const float*)d_in[12];
    const float* Wr1o  = (const float*)d_in[13];
    const float* br1o  = (const float*)d_in[14];
    const float* Wr2o  = (const float*)d_in[15];
    const float* br2o  = (const float*)d_in[16];
    const float* Wpsi1 = (const float*)d_in[17];
    const float* bpsi1 = (const float*)d_in[18];
    const float* Wpsi2 = (const float*)d_in[19];
    const float* bpsi2 = (const float*)d_in[20];
    float* out = (float*)d_out;

    int nb = in_sizes[0] / XW;               // 131072
    short* wsf = (short*)d_ws;               // 68 KB frag table

    bn_prep<<<N_FRAGS, 64, 0, stream>>>(Wp1n, Wp2n, Wr1n, Wr2n,
                                        Wp1o, Wp2o, Wr1o, Wr2o,
                                        Wpsi1, Wpsi2, wsf);

    int groups = (nb + 15) / 16;
    int blocks = (groups + 3) / 4;
    bn_main<<<blocks, 256, 0, stream>>>(x, wsf,
                                        bp1n, bp2n, br1n, br2n,
                                        bp1o, bp2o, br1o, br2o,
                                        bpsi1, bpsi2, out, nb);
}

// Round 10
// 158.632 us; speedup vs baseline: 1.4674x; 1.1120x over previous
//
#include <hip/hip_runtime.h>
#include <math.h>

// ---------------------------------------------------------------------------
// Barrier_Net, full-f16 MFMA (16x16x32).  R8 evidence: f16-rounding the
// weight side was invisible at the bf16-granularity compare (absmax stayed
// at the 0.0078 floor), so activations are f16-rounded too -> 1 MFMA/tile,
// 1 ds_read_b128 per A-frag (no perm unpack), single-cvt packing.
// One wave = 16 batch rows end-to-end; stages round-trip wave-private LDS
// ([row][k] f16).  No __syncthreads anywhere.
// A-frag: A[m=lane&15][k=(lane>>4)*8+j]; B-frag: B[k=(lane>>4)*8+j][n=lane&15]
// C/D: col=lane&15, row=(lane>>4)*4+reg.   (verified on HW by R7/R8 passing)
// K/N padding via zero-filled B-frag rows (junk A slots x 0 = 0; LDS junk
// zones zeroed once so values stay finite).
// Epilogue stores use cndmask-selected per-quad columns -> all 64 lanes hit
// distinct addresses (R8's 917K same-address write conflicts -> 0).
// ---------------------------------------------------------------------------

typedef __attribute__((ext_vector_type(8))) _Float16 f16x8;
typedef __attribute__((ext_vector_type(2))) __fp16 fp16x2;   // cvt_pkrtz's type
typedef __attribute__((ext_vector_type(4))) float f32x4;

#define XW 85   // floats per input row

// ---- B-frag table in d_ws: 34 frags x 64 lanes x 8 f16 (~34 KB) ----
#define FR_S1N  0    // Wp1n (K=4,  N=64) nt 0..3
#define FR_S1O  4    // Wp1o (K=2,  N=64) nt 0..3
#define FR_G2N  8    // Wp2n (K=64, N=16) kk 0..1
#define FR_G2O  10   // Wp2o
#define FR_RNA  12   // Wr1n (K=16, N=64) nt 0..3
#define FR_RNB  16   // Wr2n (K=64, N=16) kk 0..1
#define FR_ROA  18   // Wr1o
#define FR_ROB  22   // Wr2o
#define FR_PSI1 24   // Wpsi1(K=36, N=64) kk 0..1 x nt 0..3
#define FR_PSI2 32   // Wpsi2(K=64, N=2)  kk 0..1
#define N_FRAGS 34

// ---- per-wave LDS layout (bytes); strides multiple of 16 for b128 reads ----
#define BIG_STR 144   // 16 rows x (128 B data + pad)
#define PHI_STR 80    // 16 rows x (32 B data + 32 B zero + pad)
#define CAT_STR 144   // 16 rows x (72 B data + zeros to 128 + pad)
#define L_BIG 0
#define L_PHI 2304
#define L_CAT 3584
#define L_OUT 5888
#define L_BAR 6016
#define WAVE_LDS 6144   // x4 waves = 24576 B/block -> 6 blocks/CU

__device__ __forceinline__ float fast_rcp(float x)  { return __builtin_amdgcn_rcpf(x); }
__device__ __forceinline__ float fast_sqrt(float x) { return __builtin_amdgcn_sqrtf(x); }

__device__ __forceinline__ float two_tanh(float a) {
    float ax = fabsf(a);
    float e = __expf(2.0f * ax);
    float t = 1.0f - 2.0f * fast_rcp(e + 1.0f);
    return copysignf(2.0f * t, a);
}

__device__ __forceinline__ void lds_fence() {
    __asm__ __volatile__("s_waitcnt lgkmcnt(0)" ::: "memory");
}

__device__ __forceinline__ unsigned pk2(float a, float b) {
    union { fp16x2 h; unsigned u; } t;
    t.h = __builtin_amdgcn_cvt_pkrtz(a, b);
    return t.u;
}
__device__ __forceinline__ f16x8 make_a4(float f0, float f1, float f2, float f3) {
    union { unsigned u[4]; f16x8 v; } U;
    U.u[0] = pk2(f0, f1); U.u[1] = pk2(f2, f3); U.u[2] = 0; U.u[3] = 0;
    return U.v;
}
__device__ __forceinline__ f16x8 make_a2(float f0, float f1) {
    union { unsigned u[4]; f16x8 v; } U;
    U.u[0] = pk2(f0, f1); U.u[1] = 0; U.u[2] = 0; U.u[3] = 0;
    return U.v;
}
__device__ __forceinline__ f16x8 lds_af(const char* area, int stride, int off, int lane) {
    int mm = lane & 15, qq = lane >> 4;
    return *(const f16x8*)(area + mm * stride + off + qq * 16);
}
__device__ __forceinline__ f16x8 load_bh(const _Float16* wsf, int frag, int lane) {
    return ((const f16x8*)(wsf + (size_t)frag * 512))[lane];
}
__device__ __forceinline__ f32x4 cinit(float b) {
    f32x4 c; c[0] = b; c[1] = b; c[2] = b; c[3] = b; return c;
}
__device__ __forceinline__ f32x4 mfma1(f16x8 a, f16x8 b, f32x4 c) {
    return __builtin_amdgcn_mfma_f32_16x16x32_f16(a, b, c, 0, 0, 0);
}

// ---------------------------------------------------------------------------
// prep: pack weights into f16 B-frag blocks, zero outside (K,N).
// ---------------------------------------------------------------------------
__global__ void bn_prep(const float* __restrict__ Wp1n, const float* __restrict__ Wp2n,
                        const float* __restrict__ Wr1n, const float* __restrict__ Wr2n,
                        const float* __restrict__ Wp1o, const float* __restrict__ Wp2o,
                        const float* __restrict__ Wr1o, const float* __restrict__ Wr2o,
                        const float* __restrict__ Wpsi1, const float* __restrict__ Wpsi2,
                        _Float16* __restrict__ wsf)
{
    int f = blockIdx.x;
    int lane = threadIdx.x;   // 64
    const float* W; int K, N, kk = 0, nt = 0, rel;
    if (f < 4)        { W = Wp1n;  K = 4;  N = 64; nt = f; }
    else if (f < 8)   { W = Wp1o;  K = 2;  N = 64; nt = f - 4; }
    else if (f < 10)  { W = Wp2n;  K = 64; N = 16; kk = f - 8; }
    else if (f < 12)  { W = Wp2o;  K = 64; N = 16; kk = f - 10; }
    else if (f < 16)  { W = Wr1n;  K = 16; N = 64; nt = f - 12; }
    else if (f < 18)  { W = Wr2n;  K = 64; N = 16; kk = f - 16; }
    else if (f < 22)  { W = Wr1o;  K = 16; N = 64; nt = f - 18; }
    else if (f < 24)  { W = Wr2o;  K = 64; N = 16; kk = f - 22; }
    else if (f < 32)  { rel = f - 24; W = Wpsi1; K = 36; N = 64; kk = rel >> 2; nt = rel & 3; }
    else              { W = Wpsi2; K = 64; N = 2;  kk = f - 32; }

    int q = lane >> 4, c = lane & 15;
    _Float16* dst = wsf + (size_t)f * 512 + lane * 8;
    for (int j = 0; j < 8; ++j) {
        int k = kk * 32 + q * 8 + j;
        int n = nt * 16 + c;
        float v = (k < K && n < N) ? W[k * N + n] : 0.f;
        dst[j] = (_Float16)v;
    }
}

// ---------------------------------------------------------------------------
// main: 1 wave = 16 rows; block 256 = 4 waves.
// ---------------------------------------------------------------------------
__global__ __launch_bounds__(256) void bn_main(
    const float* __restrict__ x, const _Float16* __restrict__ wsf,
    const float* __restrict__ bp1n, const float* __restrict__ bp2n,
    const float* __restrict__ br1n, const float* __restrict__ br2n,
    const float* __restrict__ bp1o, const float* __restrict__ bp2o,
    const float* __restrict__ br1o, const float* __restrict__ br2o,
    const float* __restrict__ bpsi1, const float* __restrict__ bpsi2,
    float* __restrict__ out, int nb)
{
    __shared__ char smem[4 * WAVE_LDS];
    const int lane = threadIdx.x & 63;
    const int wid  = threadIdx.x >> 6;
    const int group = blockIdx.x * 4 + wid;
    const int row0 = group * 16;
    if (row0 >= nb) return;

    char* Wl   = smem + wid * WAVE_LDS;
    char* BIG  = Wl + L_BIG;
    char* PHI  = Wl + L_PHI;
    char* CAT  = Wl + L_CAT;
    char* OUTA = Wl + L_OUT;
    char* BAR  = Wl + L_BAR;

    const int m = lane & 15, q = lane >> 4, c = m;
    const bool q1b = (q & 1), q2b = (q & 2);

    // zero junk zones once: PHI bytes 32..63, CAT bytes 64..127 (per row)
    for (int i = lane; i < 128; i += 64) {
        int r = i >> 3, d = i & 7;
        *(unsigned*)(PHI + r * PHI_STR + 32 + d * 4) = 0;
    }
    for (int i = lane; i < 256; i += 64) {
        int r = i >> 4, d = i & 15;
        *(unsigned*)(CAT + r * CAT_STR + 64 + d * 4) = 0;
    }
    lds_fence();

    // ---- barrier terms: lane (row=m, quad q) handles nbrs 4q..4q+3 and
    //      obstacles 2q..2q+1; 4 shuffles total ----
    {
        const float* xb = x + (size_t)(row0 + m) * XW;
        float bx = 0.f, by = 0.f;
        #pragma unroll
        for (int i = 0; i < 4; ++i) {
            int n = 4 * q + i;
            float px = -xb[5 + 4 * n], py = -xb[6 + 4 * n];
            float nrm = fast_sqrt(px * px + py * py);
            float coef = 0.05f * fast_rcp(nrm * (nrm - 0.3f));
            bx = fmaf(coef, px, bx);
            by = fmaf(coef, py, by);
        }
        #pragma unroll
        for (int i = 0; i < 2; ++i) {
            int o = 2 * q + i;
            float px = -xb[69 + 2 * o], py = -xb[70 + 2 * o];
            float nrm = fast_sqrt(px * px + py * py);
            float coef = 0.05f * fast_rcp(nrm * (nrm - 0.3f));
            bx = fmaf(coef, px, bx);
            by = fmaf(coef, py, by);
        }
        bx += __shfl_xor(bx, 16); by += __shfl_xor(by, 16);
        bx += __shfl_xor(bx, 32); by += __shfl_xor(by, 32);
        if (q == 0) { float2 bb; bb.x = bx; bb.y = by; *(float2*)(BAR + m * 8) = bb; }
    }

    // g -> CAT k=32..35 (bytes 64..71); after zero-fence so order is safe
    if (lane < 16) {
        const float* xr = x + (size_t)(row0 + lane) * XW;
        uint2 gv;
        gv.x = pk2(xr[1], xr[2]);
        gv.y = pk2(xr[3], xr[4]);
        *(uint2*)(CAT + lane * CAT_STR + 64) = gv;
    }

    // biases (per output column c)
    float b_s1n[4], b_s1o[4], b_rna[4], b_roa[4], b_p1[4];
    #pragma unroll
    for (int nt = 0; nt < 4; ++nt) {
        b_s1n[nt] = bp1n[nt * 16 + c];
        b_s1o[nt] = bp1o[nt * 16 + c];
        b_rna[nt] = br1n[nt * 16 + c];
        b_roa[nt] = br1o[nt * 16 + c];
        b_p1[nt]  = bpsi1[nt * 16 + c];
    }
    float b_g2n = 16.f * bp2n[c];
    float b_g2o = 8.f * bp2o[c];
    float b_rnb = br2n[c];
    float b_rob = br2o[c];
    float b_p2  = (c < 2) ? bpsi2[c] : 0.f;

    // stage-ahead B-frags for S1N + G2N
    f16x8 Bs1n[4], Bg2n[2];
    #pragma unroll
    for (int nt = 0; nt < 4; ++nt) Bs1n[nt] = load_bh(wsf, FR_S1N + nt, lane);
    Bg2n[0] = load_bh(wsf, FR_G2N + 0, lane);
    Bg2n[1] = load_bh(wsf, FR_G2N + 1, lane);

    // ================= S1N: neighbor stage-1, software-pipelined ============
    // Sn[r][k] = sum_n relu(e_n . W1n[:,k] + b); M=nbr, reduce via 2 shuffles;
    // each quad then stores its own nt-column block -> 64 distinct addresses.
    {
        const float* xr0 = x + (size_t)row0 * XW + 5 + 4 * m;
        float c0 = xr0[0], c1 = xr0[1], c2 = xr0[2], c3 = xr0[3];
        #pragma unroll 4
        for (int r = 0; r < 16; ++r) {
            int rn = (r + 1) & 15;     // wraps (harmless)
            const float* xrn = x + (size_t)(row0 + rn) * XW + 5 + 4 * m;
            float n0 = xrn[0], n1 = xrn[1], n2 = xrn[2], n3 = xrn[3];
            f16x8 A = make_a4(c0, c1, c2, c3);
            float sv[4];
            #pragma unroll
            for (int nt = 0; nt < 4; ++nt) {
                f32x4 cc = mfma1(A, Bs1n[nt], cinit(b_s1n[nt]));
                float s = fmaxf(cc[0], 0.f) + fmaxf(cc[1], 0.f)
                        + fmaxf(cc[2], 0.f) + fmaxf(cc[3], 0.f);
                s += __shfl_xor(s, 16);
                s += __shfl_xor(s, 32);
                sv[nt] = s;
            }
            float w = q2b ? (q1b ? sv[3] : sv[2]) : (q1b ? sv[1] : sv[0]);
            *(_Float16*)(BIG + r * BIG_STR + (q * 16 + c) * 2) = (_Float16)w;
            c0 = n0; c1 = n1; c2 = n2; c3 = n3;
        }
    }
    f16x8 Brna[4];
    #pragma unroll
    for (int nt = 0; nt < 4; ++nt) Brna[nt] = load_bh(wsf, FR_RNA + nt, lane);
    lds_fence();

    // ================= G2N: Sn @ Wp2n -> phi_n (PHI) ========================
    {
        f16x8 A0 = lds_af(BIG, BIG_STR, 0, lane);
        f16x8 A1 = lds_af(BIG, BIG_STR, 64, lane);
        f32x4 ca = mfma1(A0, Bg2n[0], cinit(b_g2n));
        f32x4 cb = mfma1(A1, Bg2n[1], cinit(0.f));
        #pragma unroll
        for (int reg = 0; reg < 4; ++reg)
            *(_Float16*)(PHI + (q * 4 + reg) * PHI_STR + c * 2) = (_Float16)(ca[reg] + cb[reg]);
    }
    f16x8 Brnb[2], Bs1o[4];
    Brnb[0] = load_bh(wsf, FR_RNB + 0, lane);
    Brnb[1] = load_bh(wsf, FR_RNB + 1, lane);
    #pragma unroll
    for (int nt = 0; nt < 4; ++nt) Bs1o[nt] = load_bh(wsf, FR_S1O + nt, lane);
    lds_fence();

    // ================= RNA: relu(phi_n @ Wr1n + b) -> h2 (BIG) ==============
    {
        f16x8 A = lds_af(PHI, PHI_STR, 0, lane);   // k>=16 zero-filled
        #pragma unroll
        for (int nt = 0; nt < 4; ++nt) {
            f32x4 cc = mfma1(A, Brna[nt], cinit(b_rna[nt]));
            #pragma unroll
            for (int reg = 0; reg < 4; ++reg)
                *(_Float16*)(BIG + (q * 4 + reg) * BIG_STR + (nt * 16 + c) * 2) = (_Float16)fmaxf(cc[reg], 0.f);
        }
    }
    // prefetch: G2O frags + S1O x-data (used 2 stages ahead)
    f16x8 Bg2o[2];
    Bg2o[0] = load_bh(wsf, FR_G2O + 0, lane);
    Bg2o[1] = load_bh(wsf, FR_G2O + 1, lane);
    float of0[8], of1[8];
    #pragma unroll
    for (int t = 0; t < 8; ++t) {
        const float* xo = x + (size_t)(row0 + 2 * t + (m >> 3)) * XW + 69 + 2 * (m & 7);
        of0[t] = xo[0]; of1[t] = xo[1];
    }
    lds_fence();

    // ================= RNB: h2 @ Wr2n + b -> rho_n (CAT k=0..15) ============
    {
        f16x8 A0 = lds_af(BIG, BIG_STR, 0, lane);
        f16x8 A1 = lds_af(BIG, BIG_STR, 64, lane);
        f32x4 ca = mfma1(A0, Brnb[0], cinit(b_rnb));
        f32x4 cb = mfma1(A1, Brnb[1], cinit(0.f));
        #pragma unroll
        for (int reg = 0; reg < 4; ++reg)
            *(_Float16*)(CAT + (q * 4 + reg) * CAT_STR + c * 2) = (_Float16)(ca[reg] + cb[reg]);
    }
    f16x8 Broa[4];
    #pragma unroll
    for (int nt = 0; nt < 4; ++nt) Broa[nt] = load_bh(wsf, FR_ROA + nt, lane);
    lds_fence();

    // ================= S1O: obstacle stage-1 ================================
    // lane m: obstacle m&7 of row 2t+(m>>3); after shfl(16), q0/q1 hold row-2t
    // sums and q2/q3 row-2t+1; each quad stores 2 distinct nt-columns.
    {
        #pragma unroll
        for (int t = 0; t < 8; ++t) {
            f16x8 A = make_a2(of0[t], of1[t]);
            float sv[4];
            #pragma unroll
            for (int nt = 0; nt < 4; ++nt) {
                f32x4 cc = mfma1(A, Bs1o[nt], cinit(b_s1o[nt]));
                float s = fmaxf(cc[0], 0.f) + fmaxf(cc[1], 0.f)
                        + fmaxf(cc[2], 0.f) + fmaxf(cc[3], 0.f);
                s += __shfl_xor(s, 16);
                sv[nt] = s;
            }
            float w1 = q1b ? sv[1] : sv[0];
            float w2 = q1b ? sv[3] : sv[2];
            char* p = BIG + (2 * t + (q >> 1)) * BIG_STR + ((q & 1) * 16 + c) * 2;
            *(_Float16*)(p)      = (_Float16)w1;   // cols 0..31
            *(_Float16*)(p + 64) = (_Float16)w2;   // cols 32..63
        }
    }
    f16x8 Brob[2];
    Brob[0] = load_bh(wsf, FR_ROB + 0, lane);
    Brob[1] = load_bh(wsf, FR_ROB + 1, lane);
    lds_fence();

    // ================= G2O -> PHI ===========================================
    {
        f16x8 A0 = lds_af(BIG, BIG_STR, 0, lane);
        f16x8 A1 = lds_af(BIG, BIG_STR, 64, lane);
        f32x4 ca = mfma1(A0, Bg2o[0], cinit(b_g2o));
        f32x4 cb = mfma1(A1, Bg2o[1], cinit(0.f));
        #pragma unroll
        for (int reg = 0; reg < 4; ++reg)
            *(_Float16*)(PHI + (q * 4 + reg) * PHI_STR + c * 2) = (_Float16)(ca[reg] + cb[reg]);
    }
    f16x8 Bp1a[4];
    #pragma unroll
    for (int nt = 0; nt < 4; ++nt) Bp1a[nt] = load_bh(wsf, FR_PSI1 + nt, lane);
    lds_fence();

    // ================= ROA -> BIG ===========================================
    {
        f16x8 A = lds_af(PHI, PHI_STR, 0, lane);
        #pragma unroll
        for (int nt = 0; nt < 4; ++nt) {
            f32x4 cc = mfma1(A, Broa[nt], cinit(b_roa[nt]));
            #pragma unroll
            for (int reg = 0; reg < 4; ++reg)
                *(_Float16*)(BIG + (q * 4 + reg) * BIG_STR + (nt * 16 + c) * 2) = (_Float16)fmaxf(cc[reg], 0.f);
        }
    }
    f16x8 Bp1b[4], Bp2[2];
    #pragma unroll
    for (int nt = 0; nt < 4; ++nt) Bp1b[nt] = load_bh(wsf, FR_PSI1 + 4 + nt, lane);
    Bp2[0] = load_bh(wsf, FR_PSI2 + 0, lane);
    Bp2[1] = load_bh(wsf, FR_PSI2 + 1, lane);
    lds_fence();

    // ================= ROB: h2o @ Wr2o + b -> rho_o (CAT k=16..31) ==========
    {
        f16x8 A0 = lds_af(BIG, BIG_STR, 0, lane);
        f16x8 A1 = lds_af(BIG, BIG_STR, 64, lane);
        f32x4 ca = mfma1(A0, Brob[0], cinit(b_rob));
        f32x4 cb = mfma1(A1, Brob[1], cinit(0.f));
        #pragma unroll
        for (int reg = 0; reg < 4; ++reg)
            *(_Float16*)(CAT + (q * 4 + reg) * CAT_STR + (16 + c) * 2) = (_Float16)(ca[reg] + cb[reg]);
    }
    lds_fence();

    // ================= PSI1: [rho_n|rho_o|g] @ Wpsi1 -> h3 (BIG) ============
    {
        f16x8 A0 = lds_af(CAT, CAT_STR, 0, lane);    // k 0..31
        f16x8 A1 = lds_af(CAT, CAT_STR, 64, lane);   // k 32..63 (36..63 zero)
        #pragma unroll
        for (int nt = 0; nt < 4; ++nt) {
            f32x4 ca = mfma1(A0, Bp1a[nt], cinit(b_p1[nt]));
            f32x4 cb = mfma1(A1, Bp1b[nt], cinit(0.f));
            #pragma unroll
            for (int reg = 0; reg < 4; ++reg)
                *(_Float16*)(BIG + (q * 4 + reg) * BIG_STR + (nt * 16 + c) * 2) = (_Float16)fmaxf(ca[reg] + cb[reg], 0.f);
        }
    }
    lds_fence();

    // ================= PSI2: h3 @ Wpsi2 -> a0,a1 ============================
    {
        f16x8 A0 = lds_af(BIG, BIG_STR, 0, lane);
        f16x8 A1 = lds_af(BIG, BIG_STR, 64, lane);
        f32x4 ca = mfma1(A0, Bp2[0], cinit(b_p2));
        f32x4 cb = mfma1(A1, Bp2[1], cinit(0.f));
        if (c < 2) {
            #pragma unroll
            for (int reg = 0; reg < 4; ++reg)
                *(float*)(OUTA + (q * 4 + reg) * 8 + c * 4) = ca[reg] + cb[reg];
        }
    }
    lds_fence();

    // ================= epilogue =============================================
    if (lane < 16) {
        float2 a  = *(const float2*)(OUTA + lane * 8);
        float2 bb = *(const float2*)(BAR + lane * 8);
        float a0 = two_tanh(a.x) + bb.x;
        float a1 = two_tanh(a.y) + bb.y;
        float amax = fmaxf(fabsf(a0), fabsf(a1));
        float inv_alpha = fmaxf(amax * 0.5f, 1.0f);
        float rr = fast_rcp(inv_alpha);
        float2 o; o.x = a0 * rr; o.y = a1 * rr;
        *(float2*)(out + (size_t)(row0 + lane) * 2) = o;
    }
}

extern "C" void kernel_launch(void* const* d_in, const int* in_sizes, int n_in,
                              void* d_out, int out_size, void* d_ws, size_t ws_size,
                              hipStream_t stream) {
    const float* x     = (const float*)d_in[0];
    const float* Wp1n  = (const float*)d_in[1];
    const float* bp1n  = (const float*)d_in[2];
    const float* Wp2n  = (const float*)d_in[3];
    const float* bp2n  = (const float*)d_in[4];
    const float* Wr1n  = (const float*)d_in[5];
    const float* br1n  = (const float*)d_in[6];
    const float* Wr2n  = (const float*)d_in[7];
    const float* br2n  = (const float*)d_in[8];
    const float* Wp1o  = (const float*)d_in[9];
    const float* bp1o  = (const float*)d_in[10];
    const float* Wp2o  = (const float*)d_in[11];
    const float* bp2o  = (const float*)d_in[12];
    const float* Wr1o  = (const float*)d_in[13];
    const float* br1o  = (const float*)d_in[14];
    const float* Wr2o  = (const float*)d_in[15];
    const float* br2o  = (const float*)d_in[16];
    const float* Wpsi1 = (const float*)d_in[17];
    const float* bpsi1 = (const float*)d_in[18];
    const float* Wpsi2 = (const float*)d_in[19];
    const float* bpsi2 = (const float*)d_in[20];
    float* out = (float*)d_out;

    int nb = in_sizes[0] / XW;               // 131072
    _Float16* wsf = (_Float16*)d_ws;         // ~34 KB frag table

    bn_prep<<<N_FRAGS, 64, 0, stream>>>(Wp1n, Wp2n, Wr1n, Wr2n,
                                        Wp1o, Wp2o, Wr1o, Wr2o,
                                        Wpsi1, Wpsi2, wsf);

    int groups = (nb + 15) / 16;
    int blocks = (groups + 3) / 4;
    bn_main<<<blocks, 256, 0, stream>>>(x, wsf,
                                        bp1n, bp2n, br1n, br2n,
                                        bp1o, bp2o, br1o, br2o,
                                        bpsi1, bpsi2, out, nb);
}